// Round 11
// baseline (708.743 us; speedup 1.0000x reference)
//
#include <hip/hip_runtime.h>
#include <hip/hip_bf16.h>
#include <math.h>

#define NN 50000
#define NE 800000
#define NG 64
#define NC 100
#define EPSV 1e-5f
#define PBN 256   // BN partial-sum slots (deterministic, no atomics)
#define SCB 196   // scan blocks (196*256 >= NN)
#define SPL 8     // pool splits per graph
#define PRB 128   // poolred stage-A blocks

typedef unsigned int   u32;
typedef unsigned short u16;
typedef __attribute__((ext_vector_type(8))) short bf16x8;
typedef __attribute__((ext_vector_type(4))) float f32x4;

__device__ __forceinline__ float gelu_f(float x){
  return 0.5f*x*(1.0f + erff(x*0.70710678118654752f));
}
__device__ __forceinline__ float bf2f(u16 u){
  return __uint_as_float(((u32)u)<<16);
}
__device__ __forceinline__ float2 bf2f2(u32 u){
  float2 r;
  r.x = __uint_as_float(u<<16);
  r.y = __uint_as_float(u & 0xffff0000u);
  return r;
}
__device__ __forceinline__ u16 f2bf(float f){
  __hip_bfloat16 h = __float2bfloat16(f);
  return *(u16*)&h;
}
__device__ __forceinline__ u32 pack_bf2(float a, float b){
  return (u32)f2bf(a) | ((u32)f2bf(b)<<16);
}

// ---------------- CSR construction ----------------
__global__ void k_deg_init(int* deg){
  int i = blockIdx.x*256 + threadIdx.x;
  if (i < NN) deg[i] = 1;           // self loop
}
__global__ void k_deg_hist(const int* ei, int* deg){
  int e = blockIdx.x*256 + threadIdx.x;
  if (e < NE) atomicAdd(&deg[ei[NE + e]], 1);   // dst row
}
// partial sums of (deg-1) + dis = rsqrt(deg), fused
__global__ void k_scanA(const int* deg, int* bsum, float* dis){
  __shared__ int red[256];
  int b = blockIdx.x, t = threadIdx.x;
  int i = b*256 + t;
  int d = (i < NN) ? deg[i] : 1;
  if (i < NN) dis[i] = rsqrtf((float)d);
  red[t] = (i < NN) ? d-1 : 0;
  __syncthreads();
  for (int st = 128; st; st >>= 1){
    if (t < st) red[t] += red[t+st];
    __syncthreads();
  }
  if (t == 0) bsum[b] = red[0];
}
__global__ void k_scanB(const int* bsum, int* boff){
  __shared__ int sh[256];
  int t = threadIdx.x;
  sh[t] = (t < SCB) ? bsum[t] : 0;
  __syncthreads();
  for (int d = 1; d < 256; d <<= 1){
    int v = (t >= d) ? sh[t-d] : 0;
    __syncthreads();
    sh[t] += v;
    __syncthreads();
  }
  if (t == 0) boff[0] = 0;
  if (t < SCB) boff[t+1] = sh[t];
}
__global__ void k_scanC(const int* deg, const int* boff, int* off, int* cur){
  __shared__ int sh[256];
  int b = blockIdx.x, t = threadIdx.x;
  int i = b*256 + t;
  int v = (i < NN) ? deg[i]-1 : 0;
  sh[t] = v;
  __syncthreads();
  for (int d = 1; d < 256; d <<= 1){
    int u = (t >= d) ? sh[t-d] : 0;
    __syncthreads();
    sh[t] += u;
    __syncthreads();
  }
  if (i < NN){
    int excl = boff[b] + sh[t] - v;
    off[i] = excl; cur[i] = excl;
    if (i == NN-1) off[NN] = boff[b] + sh[t];
  }
}
__global__ void k_scatter(const int* ei, int* cur, u16* col){
  int e = blockIdx.x*256 + threadIdx.x;
  if (e < NE){
    int s = ei[e], d = ei[NE + e];
    int p = atomicAdd(&cur[d], 1);
    col[p] = (u16)s;
  }
}

// ---------------- GCN1: aggregate in 3-dim input space ----------------
__global__ void k_agg3(const float* x, const int* off, const u16* col,
                       const float* dis, float* aggx){
  int i = blockIdx.x*256 + threadIdx.x;
  if (i >= NN) return;
  float di = dis[i];
  float w0 = di*di;
  float a0 = w0*x[i*3], a1 = w0*x[i*3+1], a2 = w0*x[i*3+2];
  int lo = off[i], hi = off[i+1];
  for (int e = lo; e < hi; ++e){
    int s = col[e];
    float w = dis[s]*di;
    a0 += w*x[s*3]; a1 += w*x[s*3+1]; a2 += w*x[s*3+2];
  }
  aggx[i*3] = a0; aggx[i*3+1] = a1; aggx[i*3+2] = a2;
}

// ---------------- input matmul (K=3) ----------------
__global__ void k_mm_in(const float* aggx, const float* w, const float* bias, u32* outp){
  int gid = blockIdx.x*256 + threadIdx.x;
  if (gid >= NN*64) return;
  int i = gid >> 6, j2 = (gid & 63)*2;
  float a = aggx[i*3]*w[j2]   + aggx[i*3+1]*w[128+j2]   + aggx[i*3+2]*w[256+j2]   + bias[j2];
  float b = aggx[i*3]*w[j2+1] + aggx[i*3+1]*w[128+j2+1] + aggx[i*3+2]*w[256+j2+1] + bias[j2+1];
  outp[gid] = pack_bf2(a, b);
}

// ---------------- B pre-conversion to bf16 fragment-major ----------------
__global__ void k_prepB(const float* B, int ldB, int K, int ncc, u16* Bf){
  int gid = blockIdx.x*256 + threadIdx.x;
  int tot = ncc*K*128;
  if (gid >= tot) return;
  int cc = gid / (K*128);
  int rem = gid - cc*(K*128);
  int k = rem >> 7, n = rem & 127;
  int c128 = k >> 7, kk = k & 127;
  int nt = n >> 4, i = n & 15;
  int ks = kk >> 5, jg = (kk >> 3) & 3, e = kk & 7;
  size_t addr = (size_t)cc*K*128 +
                ((((size_t)(c128*8 + nt)*4 + ks)*4 + jg)*16 + i)*8 + e;
  Bf[addr] = f2bf(B[(size_t)k*ldB + cc*128 + n]);
}
__global__ void k_prepBG(const float* w_gat, u16* Bf){
  int gid = blockIdx.x*256 + threadIdx.x;
  if (gid >= 640*128) return;
  int k = gid >> 7, n = gid & 127;
  int h = k >> 7, kk = k & 127;
  int nt = n >> 4, i = n & 15;
  int ks = kk >> 5, jg = (kk >> 3) & 3, e = kk & 7;
  size_t addr = ((((size_t)(h*8 + nt)*4 + ks)*4 + jg)*16 + i)*8 + e;
  Bf[addr] = f2bf(0.2f * w_gat[(size_t)kk*640 + h*128 + n]);
}

// ---------------- MFMA matmul (coalesced C store via LDS) ----------------
__global__ __launch_bounds__(256) void k_mm_mfma(const u16* A, int lda, int M, int K,
                        const u16* Bf, u16* C, int ldC, const float* bias){
  __shared__ u16 ct[64*132];
  int tid = threadIdx.x;
  int w = tid >> 6, l = tid & 63;
  int jg = l >> 4, ii = l & 15;
  int m0 = blockIdx.x*64 + w*16;
  int cc = blockIdx.y;
  int arow = m0 + ii; if (arow >= M) arow = M-1;
  const u16* Bfc = Bf + (size_t)cc*K*128;
  f32x4 acc[8] = {};
  for (int c128 = 0; c128 < (K >> 7); ++c128){
    const u16* Ar = A + (size_t)arow*lda + c128*128;
    bf16x8 af[4];
    #pragma unroll
    for (int ks = 0; ks < 4; ++ks)
      af[ks] = *(const bf16x8*)(Ar + ks*32 + jg*8);
    #pragma unroll
    for (int nt = 0; nt < 8; ++nt){
      f32x4 a4 = acc[nt];
      #pragma unroll
      for (int ks = 0; ks < 4; ++ks){
        bf16x8 bfr = *(const bf16x8*)(Bfc +
            ((((size_t)(c128*8 + nt)*4 + ks)*4 + jg)*16 + ii)*8);
        a4 = __builtin_amdgcn_mfma_f32_16x16x32_bf16(af[ks], bfr, a4, 0, 0, 0);
      }
      acc[nt] = a4;
    }
  }
  int cOut = cc*128;
  int lrow0 = w*16 + jg*4;
  #pragma unroll
  for (int nt = 0; nt < 8; ++nt){
    float bv = bias[cOut + nt*16 + ii];
    #pragma unroll
    for (int r = 0; r < 4; ++r)
      ct[(lrow0 + r)*132 + nt*16 + ii] = f2bf(acc[nt][r] + bv);
  }
  __syncthreads();
  int lr0 = tid >> 6;
  int lc = tid & 63;
  #pragma unroll
  for (int rr = 0; rr < 16; ++rr){
    int lrow = rr*4 + lr0;
    int grow = blockIdx.x*64 + lrow;
    if (grow < M)
      *(u32*)(C + (size_t)grow*ldC + cOut + lc*2) = *(const u32*)(ct + lrow*132 + lc*2);
  }
}

// ---------------- GCN aggregate in 128-dim ----------------
__global__ void k_gcn_agg64(const u16* xw, const int* off, const u16* col,
                            const float* dis, u16* out){
  int i = blockIdx.x, t = threadIdx.x;   // 64 threads
  float di = dis[i];
  float2 sv = bf2f2(((const u32*)(xw + (size_t)i*128))[t]);
  float w0 = di*di;
  float ax = w0*sv.x, ay = w0*sv.y;
  int lo = off[i], hi = off[i+1];
  int e = lo;
  for (; e + 4 <= hi; e += 4){
    int s0 = col[e], s1 = col[e+1], s2 = col[e+2], s3 = col[e+3];
    float wA = dis[s0]*di, wB = dis[s1]*di, wC = dis[s2]*di, wD = dis[s3]*di;
    float2 r0 = bf2f2(((const u32*)(xw + (size_t)s0*128))[t]);
    float2 r1 = bf2f2(((const u32*)(xw + (size_t)s1*128))[t]);
    float2 r2 = bf2f2(((const u32*)(xw + (size_t)s2*128))[t]);
    float2 r3 = bf2f2(((const u32*)(xw + (size_t)s3*128))[t]);
    ax += wA*r0.x; ay += wA*r0.y;
    ax += wB*r1.x; ay += wB*r1.y;
    ax += wC*r2.x; ay += wC*r2.y;
    ax += wD*r3.x; ay += wD*r3.y;
  }
  for (; e < hi; ++e){
    int s = col[e];
    float w = dis[s]*di;
    float2 rv = bf2f2(((const u32*)(xw + (size_t)s*128))[t]);
    ax += w*rv.x; ay += w*rv.y;
  }
  ((u32*)(out + (size_t)i*128))[t] = pack_bf2(ax, ay);
}

// ---------------- BatchNorm (vectorized partials, feature-major slots) ----------
__global__ void k_bn_part(const u16* x, int stride, int W, float* part){
  __shared__ float shs[8][132];
  __shared__ float shq[8][132];
  int t = threadIdx.x;
  int ft = t & 31, rl = t >> 5;
  int f0 = ft*4;
  int fbase = blockIdx.x*128;
  int p = blockIdx.y;
  float s0=0.f,s1=0.f,s2=0.f,s3=0.f, q0=0.f,q1=0.f,q2=0.f,q3=0.f;
  for (int r = p + PBN*rl; r < NN; r += PBN*8){
    ushort4 u = *(const ushort4*)(x + (size_t)r*stride + fbase + f0);
    float v0 = bf2f(u.x), v1 = bf2f(u.y), v2 = bf2f(u.z), v3 = bf2f(u.w);
    s0 += v0; s1 += v1; s2 += v2; s3 += v3;
    q0 += v0*v0; q1 += v1*v1; q2 += v2*v2; q3 += v3*v3;
  }
  shs[rl][f0] = s0; shs[rl][f0+1] = s1; shs[rl][f0+2] = s2; shs[rl][f0+3] = s3;
  shq[rl][f0] = q0; shq[rl][f0+1] = q1; shq[rl][f0+2] = q2; shq[rl][f0+3] = q3;
  __syncthreads();
  if (t < 128){
    float s = 0.f, q = 0.f;
    #pragma unroll
    for (int r = 0; r < 8; ++r){ s += shs[r][t]; q += shq[r][t]; }
    size_t fb = (size_t)(fbase + t)*2*PBN;
    part[fb + p] = s;
    part[fb + PBN + p] = q;
  }
}
__global__ void k_bn_fin(const float* part, const float* g, const float* be,
                         float* ss, int W, float invn){
  __shared__ float rs[256], rq[256];
  int f = blockIdx.x, t = threadIdx.x;
  size_t fb = (size_t)f*2*PBN;
  rs[t] = part[fb + t];
  rq[t] = part[fb + PBN + t];
  __syncthreads();
  for (int st = 128; st; st >>= 1){
    if (t < st){ rs[t] += rs[t+st]; rq[t] += rq[t+st]; }
    __syncthreads();
  }
  if (t == 0){
    float mean = rs[0]*invn;
    float var  = rq[0]*invn - mean*mean;
    float sc = g[f]*rsqrtf(var + EPSV);
    ss[f] = sc;
    ss[W+f] = be[f] - mean*sc;
  }
}
template<bool RES>
__global__ void k_bn_apply(const u32* x, const float* ss, const u32* res, u32* out){
  const int n = NN*64;
  for (int idx = blockIdx.x*256 + threadIdx.x; idx < n; idx += gridDim.x*256){
    int f2 = (idx & 63)*2;
    float2 v = bf2f2(x[idx]);
    v.x = gelu_f(v.x*ss[f2]   + ss[128+f2]);
    v.y = gelu_f(v.y*ss[f2+1] + ss[128+f2+1]);
    if (RES){ float2 r = bf2f2(res[idx]); v.x += r.x; v.y += r.y; }
    out[idx] = pack_bf2(v.x, v.y);
  }
}

// ---------------- GAT ----------------
__global__ void k_wv(const float* w_gat, const float* att_s, const float* att_d,
                     float* wvs, float* wvd){
  int h = blockIdx.x, c = threadIdx.x;   // 5 blocks x 128
  float ss = 0.f, sd = 0.f;
  const float* wr = w_gat + (size_t)c*640 + h*128;
  const float* as = att_s + h*128;
  const float* ad = att_d + h*128;
  for (int k = 0; k < 128; ++k){
    float wv = wr[k];
    ss += wv*as[k]; sd += wv*ad[k];
  }
  wvs[h*128+c] = ss; wvd[h*128+c] = sd;
}

// per-node scores; stride-8 output so per-edge loads are one aligned float4+float
__global__ void k_score10(const u16* h2, const float* wvs, const float* wvd,
                          float* asrc8, float* adst8){
  int i = blockIdx.x, t = threadIdx.x;   // 64
  float2 v = bf2f2(((const u32*)(h2 + (size_t)i*128))[t]);
  int f2 = 2*t;
  #pragma unroll
  for (int h = 0; h < 5; ++h){
    float vs = v.x*wvs[h*128+f2] + v.y*wvs[h*128+f2+1];
    float vd = v.x*wvd[h*128+f2] + v.y*wvd[h*128+f2+1];
    #pragma unroll
    for (int d = 32; d; d >>= 1){ vs += __shfl_xor(vs, d); vd += __shfl_xor(vd, d); }
    if (t == 0){ asrc8[i*8+h] = vs; adst8[i*8+h] = vd; }
  }
}

// fused softmax + gather: ONE edge pass; fp32 alphas; normalize at end.
// max-free softmax (scores bounded << 88), denominator = sum of the same
// fp32 numerators used for accumulation.
__global__ void k_gat_fused(const u16* h2, const int* off, const u16* col,
                            const float* asrc8, const float* adst8,
                            u16* agg5){
  int i = blockIdx.x, t = threadIdx.x;   // 64
  float2 svv = bf2f2(((const u32*)(h2 + (size_t)i*128))[t]);
  float ad[5], dn[5], ax[5], ay[5];
  #pragma unroll
  for (int h = 0; h < 5; ++h){
    ad[h] = adst8[i*8+h];
    float v = asrc8[i*8+h] + ad[h];
    v = (v > 0.f) ? v : 0.2f*v;
    float esf = expf(v);               // self-loop numerator
    dn[h] = esf;
    ax[h] = esf*svv.x; ay[h] = esf*svv.y;
  }
  int lo = off[i], hi = off[i+1];
  int e = lo;
  for (; e + 2 <= hi; e += 2){
    int s0 = col[e], s1 = col[e+1];
    float4 a03_0 = *(const float4*)(asrc8 + (size_t)s0*8);
    float  a4_0  = asrc8[(size_t)s0*8 + 4];
    float4 a03_1 = *(const float4*)(asrc8 + (size_t)s1*8);
    float  a4_1  = asrc8[(size_t)s1*8 + 4];
    float2 r0 = bf2f2(((const u32*)(h2 + (size_t)s0*128))[t]);
    float2 r1 = bf2f2(((const u32*)(h2 + (size_t)s1*128))[t]);
    float sa0[5] = {a03_0.x, a03_0.y, a03_0.z, a03_0.w, a4_0};
    float sa1[5] = {a03_1.x, a03_1.y, a03_1.z, a03_1.w, a4_1};
    #pragma unroll
    for (int h = 0; h < 5; ++h){
      float v0 = sa0[h] + ad[h]; v0 = (v0 > 0.f) ? v0 : 0.2f*v0;
      float v1 = sa1[h] + ad[h]; v1 = (v1 > 0.f) ? v1 : 0.2f*v1;
      float e0 = expf(v0), e1 = expf(v1);
      dn[h] += e0 + e1;
      ax[h] += e0*r0.x + e1*r1.x;
      ay[h] += e0*r0.y + e1*r1.y;
    }
  }
  for (; e < hi; ++e){
    int s = col[e];
    float4 a03 = *(const float4*)(asrc8 + (size_t)s*8);
    float  a4  = asrc8[(size_t)s*8 + 4];
    float2 rv = bf2f2(((const u32*)(h2 + (size_t)s*128))[t]);
    float sa[5] = {a03.x, a03.y, a03.z, a03.w, a4};
    #pragma unroll
    for (int h = 0; h < 5; ++h){
      float v = sa[h] + ad[h]; v = (v > 0.f) ? v : 0.2f*v;
      float ex = expf(v);
      dn[h] += ex;
      ax[h] += ex*rv.x;
      ay[h] += ex*rv.y;
    }
  }
  #pragma unroll
  for (int h = 0; h < 5; ++h){
    float iv = 1.f/fmaxf(dn[h], 1e-16f);
    ((u32*)(agg5 + (size_t)i*640 + h*128))[t] = pack_bf2(ax[h]*iv, ay[h]*iv);
  }
}

// ---------------- fused graph-LN stats + mean pool (single pass over A512) -------
__global__ void k_gstart(const int* batch, int* gs){
  int g = threadIdx.x;
  if (g > NG) return;
  int lo = 0, hi = NN;
  while (lo < hi){ int mid = (lo+hi) >> 1; if (batch[mid] < g) lo = mid+1; else hi = mid; }
  gs[g] = lo;
}
// grid (NG, SPL) x 512 threads: 128 f-threads (ushort4) x 4 row lanes
__global__ void k_poolstat(const u16* a512, const float* ss, const int* gs,
                           float* poolpart, float* sqpart){
  __shared__ float4 red4[512];
  __shared__ float redq[512];
  int g = blockIdx.x, sp = blockIdx.y, t = threadIdx.x;
  int ft = t & 127, rl = t >> 7;
  int f0 = ft*4;
  int lo = gs[g], hi = gs[g+1];
  float sc0 = ss[f0],     sc1 = ss[f0+1],     sc2 = ss[f0+2],     sc3 = ss[f0+3];
  float sh0 = ss[512+f0], sh1 = ss[512+f0+1], sh2 = ss[512+f0+2], sh3 = ss[512+f0+3];
  float4 s4 = {0.f,0.f,0.f,0.f};
  float q = 0.f;
  for (int r = lo + sp*4 + rl; r < hi; r += SPL*4){
    ushort4 u = *(const ushort4*)(a512 + (size_t)r*512 + f0);
    float v0 = gelu_f(bf2f(u.x)*sc0 + sh0);
    float v1 = gelu_f(bf2f(u.y)*sc1 + sh1);
    float v2 = gelu_f(bf2f(u.z)*sc2 + sh2);
    float v3 = gelu_f(bf2f(u.w)*sc3 + sh3);
    s4.x += v0; s4.y += v1; s4.z += v2; s4.w += v3;
    q += v0*v0 + v1*v1 + v2*v2 + v3*v3;
  }
  red4[t] = s4; redq[t] = q;
  __syncthreads();
  for (int st = 256; st; st >>= 1){
    if (t < st) redq[t] += redq[t+st];
    __syncthreads();
  }
  if (t == 0) sqpart[g*SPL + sp] = redq[0];
  if (rl == 0){
    float4 a = red4[t], b = red4[t+128], c = red4[t+256], d = red4[t+384];
    float4 o;
    o.x = a.x+b.x+c.x+d.x; o.y = a.y+b.y+c.y+d.y;
    o.z = a.z+b.z+c.z+d.z; o.w = a.w+b.w+c.w+d.w;
    ((float4*)poolpart)[((size_t)(g*SPL + sp))*128 + ft] = o;
  }
}
// stage A: PRB blocks x 256 threads, deterministic block partials
__global__ void k_poolredA(const float* poolpart, const float* sqpart,
                           float* ppred, float* sqred){
  __shared__ float rs_[256], rq_[256];
  int b = blockIdx.x, t = threadIdx.x;
  float s = 0.f, q = 0.f;
  const int tot = NG*SPL*512;
  for (int i = b*256 + t; i < tot; i += PRB*256) s += poolpart[i];
  for (int i = b*256 + t; i < NG*SPL; i += PRB*256) q += sqpart[i];
  rs_[t] = s; rq_[t] = q;
  __syncthreads();
  for (int st = 128; st; st >>= 1){
    if (t < st){ rs_[t] += rs_[t+st]; rq_[t] += rq_[t+st]; }
    __syncthreads();
  }
  if (t == 0){ ppred[b] = rs_[0]; sqred[b] = rq_[0]; }
}
__global__ void k_poolredB(const float* ppred, const float* sqred, float* scal){
  __shared__ float rs_[128], rq_[128];
  int t = threadIdx.x;   // 128 = PRB
  rs_[t] = ppred[t]; rq_[t] = sqred[t];
  __syncthreads();
  for (int st = 64; st; st >>= 1){
    if (t < st){ rs_[t] += rs_[t+st]; rq_[t] += rq_[t+st]; }
    __syncthreads();
  }
  if (t == 0){
    float invn = 1.f/((float)NN*512.f);
    float mu  = rs_[0]*invn;
    float var = rq_[0]*invn - mu*mu;
    scal[2] = mu;
    scal[3] = rsqrtf(var + EPSV);
  }
}
__global__ void k_poolapply(const float* poolpart, const int* gs, const float* scal,
                            const float* gam, const float* bet, float* pooled){
  int g = blockIdx.x, f = threadIdx.x;   // 512
  float s = 0.f;
  #pragma unroll
  for (int sp = 0; sp < SPL; ++sp)
    s += poolpart[((size_t)(g*SPL + sp))*512 + f];
  float cnt = (float)max(gs[g+1] - gs[g], 1);
  pooled[g*512 + f] = (s/cnt - scal[2])*scal[3]*gam[f] + bet[f];
}

// ---------------- projection head + classifier (fp32, tiny) ----------------
__global__ void k_head_mm1(const float* pooled, const float* w, const float* b, float* q){
  int g = blockIdx.x, j = threadIdx.x;   // 128
  float s = b[j];
  const float* pr = pooled + g*512;
  for (int k = 0; k < 512; ++k) s += pr[k]*w[k*128+j];
  q[g*128+j] = s;
}
__global__ void k_head_bn(const float* qin, const float* g_, const float* be_, float* qout){
  int f = threadIdx.x;   // 128, single block
  float s = 0.f, sq = 0.f;
  for (int r = 0; r < NG; ++r){ float v = qin[r*128+f]; s += v; sq += v*v; }
  float mu = s*(1.f/NG), var = sq*(1.f/NG) - mu*mu;
  float sc = g_[f]*rsqrtf(var + EPSV);
  float sh = be_[f] - mu*sc;
  for (int r = 0; r < NG; ++r) qout[r*128+f] = gelu_f(qin[r*128+f]*sc + sh);
}
// head2 (mm + res + LN + L2-normalize) fused with classifier (log-softmax)
__global__ void k_head2c(const float* q2, const float* w, const float* b,
                         const float* gam, const float* bet,
                         const float* wc, const float* bc, float* out){
  int g = blockIdx.x, j = threadIdx.x;   // 128
  __shared__ float row[128], red[128], shv[3];
  row[j] = q2[g*128+j];
  __syncthreads();
  float s = b[j] + row[j];
  for (int k = 0; k < 128; ++k) s += row[k]*w[k*128+j];
  red[j] = s; __syncthreads();
  for (int st = 64; st; st >>= 1){ if (j < st) red[j] += red[j+st]; __syncthreads(); }
  if (j == 0) shv[0] = red[0]*(1.f/128.f);
  __syncthreads();
  float d = s - shv[0];
  red[j] = d*d; __syncthreads();
  for (int st = 64; st; st >>= 1){ if (j < st) red[j] += red[j+st]; __syncthreads(); }
  if (j == 0) shv[1] = rsqrtf(red[0]*(1.f/128.f) + EPSV);
  __syncthreads();
  float v = d*shv[1]*gam[j] + bet[j];
  red[j] = v*v; __syncthreads();
  for (int st = 64; st; st >>= 1){ if (j < st) red[j] += red[j+st]; __syncthreads(); }
  if (j == 0) shv[2] = 1.f/fmaxf(sqrtf(red[0]), 1e-12f);
  __syncthreads();
  float o = v*shv[2];
  out[g*128+j] = o;
  __syncthreads();
  row[j] = o;        // x1 row for classifier
  __syncthreads();
  float cs = -1e30f;
  if (j < NC){
    cs = bc[j];
    for (int k = 0; k < 128; ++k) cs += row[k]*wc[k*NC+j];
  }
  red[j] = cs; __syncthreads();
  for (int st = 64; st; st >>= 1){ if (j < st) red[j] = fmaxf(red[j], red[j+st]); __syncthreads(); }
  if (j == 0) shv[0] = red[0];
  __syncthreads();
  float e = (j < NC) ? expf(cs - shv[0]) : 0.f;
  red[j] = e; __syncthreads();
  for (int st = 64; st; st >>= 1){ if (j < st) red[j] += red[j+st]; __syncthreads(); }
  if (j == 0) shv[1] = logf(red[0]);
  __syncthreads();
  if (j < NC) out[NG*128 + g*NC+j] = cs - shv[0] - shv[1];
}

extern "C" void kernel_launch(void* const* d_in, const int* in_sizes, int n_in,
                              void* d_out, int out_size, void* d_ws, size_t ws_size,
                              hipStream_t stream){
  const float* x      = (const float*)d_in[0];
  const int*   ei     = (const int*)d_in[1];
  const int*   batch  = (const int*)d_in[2];
  const float* w_in   = (const float*)d_in[3];
  const float* b_in   = (const float*)d_in[4];
  const float* g_in   = (const float*)d_in[5];
  const float* be_in  = (const float*)d_in[6];
  const float* w_h    = (const float*)d_in[7];
  const float* b_h    = (const float*)d_in[8];
  const float* g_h    = (const float*)d_in[9];
  const float* be_h   = (const float*)d_in[10];
  const float* w_gat  = (const float*)d_in[11];
  const float* att_s  = (const float*)d_in[12];
  const float* att_d  = (const float*)d_in[13];
  const float* b_gat  = (const float*)d_in[14];
  const float* w_out  = (const float*)d_in[15];
  const float* b_out  = (const float*)d_in[16];
  const float* g_out  = (const float*)d_in[17];
  const float* be_out = (const float*)d_in[18];
  const float* g_ln   = (const float*)d_in[19];
  const float* be_ln  = (const float*)d_in[20];
  const float* w_p1   = (const float*)d_in[21];
  const float* b_p1   = (const float*)d_in[22];
  const float* g_pbn  = (const float*)d_in[23];
  const float* be_pbn = (const float*)d_in[24];
  const float* w_p2   = (const float*)d_in[25];
  const float* b_p2   = (const float*)d_in[26];
  const float* g_pln  = (const float*)d_in[27];
  const float* be_pln = (const float*)d_in[28];
  const float* w_c    = (const float*)d_in[29];
  const float* b_c    = (const float*)d_in[30];
  float* out = (float*)d_out;

  char* ws = (char*)d_ws;
  size_t o = 0;
  auto carve = [&](size_t bytes) -> char* {
    char* p = ws + o;
    o += (bytes + 255) & ~(size_t)255;
    return p;
  };
  int*   deg    = (int*)  carve((size_t)NN*4);
  int*   off    = (int*)  carve((size_t)(NN+1)*4);
  int*   cur    = (int*)  carve((size_t)NN*4);
  u16*   col    = (u16*)  carve((size_t)NE*2);       // 1.6 MB (u16 node ids)
  float* dis    = (float*)carve((size_t)NN*4);
  int*   bsum   = (int*)  carve((size_t)SCB*4);
  int*   boff   = (int*)  carve((size_t)(SCB+1)*4);
  float* aggx3  = (float*)carve((size_t)NN*3*4);
  u16*   F0     = (u16*)  carve((size_t)NN*128*2);   // 12.8 MB
  u16*   F1     = (u16*)  carve((size_t)NN*128*2);
  u16*   F2     = (u16*)  carve((size_t)NN*128*2);
  u16*   AGG5   = (u16*)  carve((size_t)NN*640*2);   // 64 MB; later aliased as A512
  float* asrc8  = (float*)carve((size_t)NN*8*4);     // 1.6 MB stride-8
  float* adst8  = (float*)carve((size_t)NN*8*4);
  float* wvs    = (float*)carve(640*4);
  float* wvd    = (float*)carve(640*4);
  u16*   BfH    = (u16*)  carve((size_t)128*128*2);
  u16*   BfG    = (u16*)  carve((size_t)640*128*2);
  u16*   BfO    = (u16*)  carve((size_t)128*512*2);
  float* part   = (float*)carve((size_t)512*2*PBN*4);   // 1 MB, feature-major
  float* poolpart = (float*)carve((size_t)NG*SPL*512*4); // 1 MB
  float* sqpart = (float*)carve((size_t)NG*SPL*4);
  float* ppred  = (float*)carve((size_t)PRB*4);
  float* sqred  = (float*)carve((size_t)PRB*4);
  float* ssbuf  = (float*)carve(1024*4);
  float* scal   = (float*)carve(64);
  int*   gst    = (int*)  carve(65*4);
  float* pooled = (float*)carve((size_t)NG*512*4);
  float* q      = (float*)carve((size_t)NG*128*4);
  float* q2     = (float*)carve((size_t)NG*128*4);
  if (o > ws_size) return;   // ~117 MB total

  u16* A512 = AGG5;        // [NN,512] bf16 reuses AGG5 (dead by then)

  // ---- CSR build ----
  k_deg_init<<<196,256,0,stream>>>(deg);
  k_deg_hist<<<3125,256,0,stream>>>(ei, deg);
  k_scanA<<<SCB,256,0,stream>>>(deg, bsum, dis);
  k_scanB<<<1,256,0,stream>>>(bsum, boff);
  k_scanC<<<SCB,256,0,stream>>>(deg, boff, off, cur);
  k_scatter<<<3125,256,0,stream>>>(ei, cur, col);

  // ---- weight fragment pre-conversion (tiny, one-time) ----
  k_prepB<<<64,256,0,stream>>>(w_h, 128, 128, 1, BfH);
  k_prepBG<<<320,256,0,stream>>>(w_gat, BfG);
  k_prepB<<<256,256,0,stream>>>(w_out, 512, 128, 4, BfO);

  // ---- GCN1: agg in 3-dim, mm 3->128, BN, gelu ----
  k_agg3<<<196,256,0,stream>>>(x, off, col, dis, aggx3);
  k_mm_in<<<(NN*64+255)/256,256,0,stream>>>(aggx3, w_in, b_in, (u32*)F0);   // pre1=F0
  k_bn_part<<<dim3(1,PBN),256,0,stream>>>(F0, 128, 128, part);
  k_bn_fin<<<128,256,0,stream>>>(part, g_in, be_in, ssbuf, 128, 1.f/NN);
  k_bn_apply<false><<<2048,256,0,stream>>>((u32*)F0, ssbuf, nullptr, (u32*)F1); // h1=F1

  // ---- GCN2: agg(h1), mm 128->128 +b, BN, gelu, +res ----
  k_gcn_agg64<<<NN,64,0,stream>>>(F1, off, col, dis, F0);                   // aggH1=F0
  k_mm_mfma<<<dim3(782,1),256,0,stream>>>(F0, 128, NN, 128, BfH, F2, 128, b_h); // pre2=F2
  k_bn_part<<<dim3(1,PBN),256,0,stream>>>(F2, 128, 128, part);
  k_bn_fin<<<128,256,0,stream>>>(part, g_h, be_h, ssbuf, 128, 1.f/NN);
  k_bn_apply<true><<<2048,256,0,stream>>>((u32*)F2, ssbuf, (u32*)F1, (u32*)F0);  // h2=F0

  // ---- GAT: scores from h2, ONE fused softmax+gather edge pass, mm K=640 ----
  k_wv<<<5,128,0,stream>>>(w_gat, att_s, att_d, wvs, wvd);
  k_score10<<<NN,64,0,stream>>>(F0, wvs, wvd, asrc8, adst8);
  k_gat_fused<<<NN,64,0,stream>>>(F0, off, col, asrc8, adst8, AGG5);
  k_mm_mfma<<<dim3(782,1),256,0,stream>>>(AGG5, 640, NN, 640, BfG, F1, 128, b_gat); // h3=F1

  // ---- GCN3: agg(h3), mm 128->512 +b (one dispatch, 4 col chunks) ----
  k_gcn_agg64<<<NN,64,0,stream>>>(F1, off, col, dis, F2);                   // aggH3=F2
  k_mm_mfma<<<dim3(782,4),256,0,stream>>>(F2, 128, NN, 128, BfO, A512, 512, b_out); // pre4=A512
  k_bn_part<<<dim3(4,PBN),256,0,stream>>>(A512, 512, 512, part);
  k_bn_fin<<<512,256,0,stream>>>(part, g_out, be_out, ssbuf, 512, 1.f/NN);

  // ---- fused graph-LN stats + mean pool (single pass; h4 never materialized) ----
  k_gstart<<<1,128,0,stream>>>(batch, gst);
  k_poolstat<<<dim3(NG,SPL),512,0,stream>>>(A512, ssbuf, gst, poolpart, sqpart);
  k_poolredA<<<PRB,256,0,stream>>>(poolpart, sqpart, ppred, sqred);
  k_poolredB<<<1,128,0,stream>>>(ppred, sqred, scal);
  k_poolapply<<<NG,512,0,stream>>>(poolpart, gst, scal, g_ln, be_ln, pooled);

  // ---- projection head + classifier ----
  k_head_mm1<<<NG,128,0,stream>>>(pooled, w_p1, b_p1, q);
  k_head_bn<<<1,128,0,stream>>>(q, g_pbn, be_pbn, q2);
  k_head2c<<<NG,128,0,stream>>>(q2, w_p2, b_p2, g_pln, be_pln, w_c, b_c, out);
}

// Round 12
// 613.668 us; speedup vs baseline: 1.1549x; 1.1549x over previous
//
#include <hip/hip_runtime.h>
#include <hip/hip_bf16.h>
#include <math.h>

#define NN 50000
#define NE 800000
#define NG 64
#define NC 100
#define EPSV 1e-5f
#define PBN 256   // BN partial-sum slots (deterministic, no atomics)
#define SCB 196   // scan blocks (196*256 >= NN)
#define SPL 8     // pool splits per graph
#define PRB 128   // poolred stage-A blocks

typedef unsigned int   u32;
typedef unsigned short u16;
typedef __attribute__((ext_vector_type(8))) short bf16x8;
typedef __attribute__((ext_vector_type(4))) float f32x4;

__device__ __forceinline__ float gelu_f(float x){
  return 0.5f*x*(1.0f + erff(x*0.70710678118654752f));
}
__device__ __forceinline__ float bf2f(u16 u){
  return __uint_as_float(((u32)u)<<16);
}
__device__ __forceinline__ float2 bf2f2(u32 u){
  float2 r;
  r.x = __uint_as_float(u<<16);
  r.y = __uint_as_float(u & 0xffff0000u);
  return r;
}
__device__ __forceinline__ u16 f2bf(float f){
  __hip_bfloat16 h = __float2bfloat16(f);
  return *(u16*)&h;
}
__device__ __forceinline__ u32 pack_bf2(float a, float b){
  return (u32)f2bf(a) | ((u32)f2bf(b)<<16);
}

// ---------------- CSR construction ----------------
__global__ void k_deg_init(int* deg){
  int i = blockIdx.x*256 + threadIdx.x;
  if (i < NN) deg[i] = 1;           // self loop
}
__global__ void k_deg_hist(const int* ei, int* deg){
  int e = blockIdx.x*256 + threadIdx.x;
  if (e < NE) atomicAdd(&deg[ei[NE + e]], 1);   // dst row
}
// partial sums of (deg-1) + dis = rsqrt(deg), fused
__global__ void k_scanA(const int* deg, int* bsum, float* dis){
  __shared__ int red[256];
  int b = blockIdx.x, t = threadIdx.x;
  int i = b*256 + t;
  int d = (i < NN) ? deg[i] : 1;
  if (i < NN) dis[i] = rsqrtf((float)d);
  red[t] = (i < NN) ? d-1 : 0;
  __syncthreads();
  for (int st = 128; st; st >>= 1){
    if (t < st) red[t] += red[t+st];
    __syncthreads();
  }
  if (t == 0) bsum[b] = red[0];
}
__global__ void k_scanB(const int* bsum, int* boff){
  __shared__ int sh[256];
  int t = threadIdx.x;
  sh[t] = (t < SCB) ? bsum[t] : 0;
  __syncthreads();
  for (int d = 1; d < 256; d <<= 1){
    int v = (t >= d) ? sh[t-d] : 0;
    __syncthreads();
    sh[t] += v;
    __syncthreads();
  }
  if (t == 0) boff[0] = 0;
  if (t < SCB) boff[t+1] = sh[t];
}
__global__ void k_scanC(const int* deg, const int* boff, int* off, int* cur){
  __shared__ int sh[256];
  int b = blockIdx.x, t = threadIdx.x;
  int i = b*256 + t;
  int v = (i < NN) ? deg[i]-1 : 0;
  sh[t] = v;
  __syncthreads();
  for (int d = 1; d < 256; d <<= 1){
    int u = (t >= d) ? sh[t-d] : 0;
    __syncthreads();
    sh[t] += u;
    __syncthreads();
  }
  if (i < NN){
    int excl = boff[b] + sh[t] - v;
    off[i] = excl; cur[i] = excl;
    if (i == NN-1) off[NN] = boff[b] + sh[t];
  }
}
__global__ void k_scatter(const int* ei, int* cur, u16* col){
  int e = blockIdx.x*256 + threadIdx.x;
  if (e < NE){
    int s = ei[e], d = ei[NE + e];
    int p = atomicAdd(&cur[d], 1);
    col[p] = (u16)s;
  }
}

// ---------------- GCN1: aggregate in 3-dim input space ----------------
__global__ void k_agg3(const float* x, const int* off, const u16* col,
                       const float* dis, float* aggx){
  int i = blockIdx.x*256 + threadIdx.x;
  if (i >= NN) return;
  float di = dis[i];
  float w0 = di*di;
  float a0 = w0*x[i*3], a1 = w0*x[i*3+1], a2 = w0*x[i*3+2];
  int lo = off[i], hi = off[i+1];
  for (int e = lo; e < hi; ++e){
    int s = col[e];
    float w = dis[s]*di;
    a0 += w*x[s*3]; a1 += w*x[s*3+1]; a2 += w*x[s*3+2];
  }
  aggx[i*3] = a0; aggx[i*3+1] = a1; aggx[i*3+2] = a2;
}

// ---------------- input matmul (K=3) ----------------
__global__ void k_mm_in(const float* aggx, const float* w, const float* bias, u32* outp){
  int gid = blockIdx.x*256 + threadIdx.x;
  if (gid >= NN*64) return;
  int i = gid >> 6, j2 = (gid & 63)*2;
  float a = aggx[i*3]*w[j2]   + aggx[i*3+1]*w[128+j2]   + aggx[i*3+2]*w[256+j2]   + bias[j2];
  float b = aggx[i*3]*w[j2+1] + aggx[i*3+1]*w[128+j2+1] + aggx[i*3+2]*w[256+j2+1] + bias[j2+1];
  outp[gid] = pack_bf2(a, b);
}

// ---------------- B pre-conversion to bf16 fragment-major ----------------
__global__ void k_prepB(const float* B, int ldB, int K, int ncc, u16* Bf){
  int gid = blockIdx.x*256 + threadIdx.x;
  int tot = ncc*K*128;
  if (gid >= tot) return;
  int cc = gid / (K*128);
  int rem = gid - cc*(K*128);
  int k = rem >> 7, n = rem & 127;
  int c128 = k >> 7, kk = k & 127;
  int nt = n >> 4, i = n & 15;
  int ks = kk >> 5, jg = (kk >> 3) & 3, e = kk & 7;
  size_t addr = (size_t)cc*K*128 +
                ((((size_t)(c128*8 + nt)*4 + ks)*4 + jg)*16 + i)*8 + e;
  Bf[addr] = f2bf(B[(size_t)k*ldB + cc*128 + n]);
}
__global__ void k_prepBG(const float* w_gat, u16* Bf){
  int gid = blockIdx.x*256 + threadIdx.x;
  if (gid >= 640*128) return;
  int k = gid >> 7, n = gid & 127;
  int h = k >> 7, kk = k & 127;
  int nt = n >> 4, i = n & 15;
  int ks = kk >> 5, jg = (kk >> 3) & 3, e = kk & 7;
  size_t addr = ((((size_t)(h*8 + nt)*4 + ks)*4 + jg)*16 + i)*8 + e;
  Bf[addr] = f2bf(0.2f * w_gat[(size_t)kk*640 + h*128 + n]);
}

// ---------------- MFMA matmul (coalesced C store via LDS) ----------------
__global__ __launch_bounds__(256) void k_mm_mfma(const u16* A, int lda, int M, int K,
                        const u16* Bf, u16* C, int ldC, const float* bias){
  __shared__ u16 ct[64*132];
  int tid = threadIdx.x;
  int w = tid >> 6, l = tid & 63;
  int jg = l >> 4, ii = l & 15;
  int m0 = blockIdx.x*64 + w*16;
  int cc = blockIdx.y;
  int arow = m0 + ii; if (arow >= M) arow = M-1;
  const u16* Bfc = Bf + (size_t)cc*K*128;
  f32x4 acc[8] = {};
  for (int c128 = 0; c128 < (K >> 7); ++c128){
    const u16* Ar = A + (size_t)arow*lda + c128*128;
    bf16x8 af[4];
    #pragma unroll
    for (int ks = 0; ks < 4; ++ks)
      af[ks] = *(const bf16x8*)(Ar + ks*32 + jg*8);
    #pragma unroll
    for (int nt = 0; nt < 8; ++nt){
      f32x4 a4 = acc[nt];
      #pragma unroll
      for (int ks = 0; ks < 4; ++ks){
        bf16x8 bfr = *(const bf16x8*)(Bfc +
            ((((size_t)(c128*8 + nt)*4 + ks)*4 + jg)*16 + ii)*8);
        a4 = __builtin_amdgcn_mfma_f32_16x16x32_bf16(af[ks], bfr, a4, 0, 0, 0);
      }
      acc[nt] = a4;
    }
  }
  int cOut = cc*128;
  int lrow0 = w*16 + jg*4;
  #pragma unroll
  for (int nt = 0; nt < 8; ++nt){
    float bv = bias[cOut + nt*16 + ii];
    #pragma unroll
    for (int r = 0; r < 4; ++r)
      ct[(lrow0 + r)*132 + nt*16 + ii] = f2bf(acc[nt][r] + bv);
  }
  __syncthreads();
  int lr0 = tid >> 6;
  int lc = tid & 63;
  #pragma unroll
  for (int rr = 0; rr < 16; ++rr){
    int lrow = rr*4 + lr0;
    int grow = blockIdx.x*64 + lrow;
    if (grow < M)
      *(u32*)(C + (size_t)grow*ldC + cOut + lc*2) = *(const u32*)(ct + lrow*132 + lc*2);
  }
}

// ---------------- GCN aggregate in 128-dim ----------------
__global__ void k_gcn_agg64(const u16* xw, const int* off, const u16* col,
                            const float* dis, u16* out){
  int i = blockIdx.x, t = threadIdx.x;   // 64 threads
  float di = dis[i];
  float2 sv = bf2f2(((const u32*)(xw + (size_t)i*128))[t]);
  float w0 = di*di;
  float ax = w0*sv.x, ay = w0*sv.y;
  int lo = off[i], hi = off[i+1];
  int e = lo;
  for (; e + 4 <= hi; e += 4){
    int s0 = col[e], s1 = col[e+1], s2 = col[e+2], s3 = col[e+3];
    float wA = dis[s0]*di, wB = dis[s1]*di, wC = dis[s2]*di, wD = dis[s3]*di;
    float2 r0 = bf2f2(((const u32*)(xw + (size_t)s0*128))[t]);
    float2 r1 = bf2f2(((const u32*)(xw + (size_t)s1*128))[t]);
    float2 r2 = bf2f2(((const u32*)(xw + (size_t)s2*128))[t]);
    float2 r3 = bf2f2(((const u32*)(xw + (size_t)s3*128))[t]);
    ax += wA*r0.x; ay += wA*r0.y;
    ax += wB*r1.x; ay += wB*r1.y;
    ax += wC*r2.x; ay += wC*r2.y;
    ax += wD*r3.x; ay += wD*r3.y;
  }
  for (; e < hi; ++e){
    int s = col[e];
    float w = dis[s]*di;
    float2 rv = bf2f2(((const u32*)(xw + (size_t)s*128))[t]);
    ax += w*rv.x; ay += w*rv.y;
  }
  ((u32*)(out + (size_t)i*128))[t] = pack_bf2(ax, ay);
}

// ---------------- BatchNorm (vectorized partials, feature-major slots) ----------
__global__ void k_bn_part(const u16* x, int stride, int W, float* part){
  __shared__ float shs[8][132];
  __shared__ float shq[8][132];
  int t = threadIdx.x;
  int ft = t & 31, rl = t >> 5;
  int f0 = ft*4;
  int fbase = blockIdx.x*128;
  int p = blockIdx.y;
  float s0=0.f,s1=0.f,s2=0.f,s3=0.f, q0=0.f,q1=0.f,q2=0.f,q3=0.f;
  for (int r = p + PBN*rl; r < NN; r += PBN*8){
    ushort4 u = *(const ushort4*)(x + (size_t)r*stride + fbase + f0);
    float v0 = bf2f(u.x), v1 = bf2f(u.y), v2 = bf2f(u.z), v3 = bf2f(u.w);
    s0 += v0; s1 += v1; s2 += v2; s3 += v3;
    q0 += v0*v0; q1 += v1*v1; q2 += v2*v2; q3 += v3*v3;
  }
  shs[rl][f0] = s0; shs[rl][f0+1] = s1; shs[rl][f0+2] = s2; shs[rl][f0+3] = s3;
  shq[rl][f0] = q0; shq[rl][f0+1] = q1; shq[rl][f0+2] = q2; shq[rl][f0+3] = q3;
  __syncthreads();
  if (t < 128){
    float s = 0.f, q = 0.f;
    #pragma unroll
    for (int r = 0; r < 8; ++r){ s += shs[r][t]; q += shq[r][t]; }
    size_t fb = (size_t)(fbase + t)*2*PBN;
    part[fb + p] = s;
    part[fb + PBN + p] = q;
  }
}
__global__ void k_bn_fin(const float* part, const float* g, const float* be,
                         float* ss, int W, float invn){
  __shared__ float rs[256], rq[256];
  int f = blockIdx.x, t = threadIdx.x;
  size_t fb = (size_t)f*2*PBN;
  rs[t] = part[fb + t];
  rq[t] = part[fb + PBN + t];
  __syncthreads();
  for (int st = 128; st; st >>= 1){
    if (t < st){ rs[t] += rs[t+st]; rq[t] += rq[t+st]; }
    __syncthreads();
  }
  if (t == 0){
    float mean = rs[0]*invn;
    float var  = rq[0]*invn - mean*mean;
    float sc = g[f]*rsqrtf(var + EPSV);
    ss[f] = sc;
    ss[W+f] = be[f] - mean*sc;
  }
}
template<bool RES>
__global__ void k_bn_apply(const u32* x, const float* ss, const u32* res, u32* out){
  const int n = NN*64;
  for (int idx = blockIdx.x*256 + threadIdx.x; idx < n; idx += gridDim.x*256){
    int f2 = (idx & 63)*2;
    float2 v = bf2f2(x[idx]);
    v.x = gelu_f(v.x*ss[f2]   + ss[128+f2]);
    v.y = gelu_f(v.y*ss[f2+1] + ss[128+f2+1]);
    if (RES){ float2 r = bf2f2(res[idx]); v.x += r.x; v.y += r.y; }
    out[idx] = pack_bf2(v.x, v.y);
  }
}

// ---------------- GAT ----------------
__global__ void k_wv(const float* w_gat, const float* att_s, const float* att_d,
                     float* wvs, float* wvd){
  int h = blockIdx.x, c = threadIdx.x;   // 5 blocks x 128
  float ss = 0.f, sd = 0.f;
  const float* wr = w_gat + (size_t)c*640 + h*128;
  const float* as = att_s + h*128;
  const float* ad = att_d + h*128;
  for (int k = 0; k < 128; ++k){
    float wv = wr[k];
    ss += wv*as[k]; sd += wv*ad[k];
  }
  wvs[h*128+c] = ss; wvd[h*128+c] = sd;
}

// per-node scores; stride-8 output so per-edge loads are one aligned float4+float
__global__ void k_score10(const u16* h2, const float* wvs, const float* wvd,
                          float* asrc8, float* adst8){
  int i = blockIdx.x, t = threadIdx.x;   // 64
  float2 v = bf2f2(((const u32*)(h2 + (size_t)i*128))[t]);
  int f2 = 2*t;
  #pragma unroll
  for (int h = 0; h < 5; ++h){
    float vs = v.x*wvs[h*128+f2] + v.y*wvs[h*128+f2+1];
    float vd = v.x*wvd[h*128+f2] + v.y*wvd[h*128+f2+1];
    #pragma unroll
    for (int d = 32; d; d >>= 1){ vs += __shfl_xor(vs, d); vd += __shfl_xor(vd, d); }
    if (t == 0){ asrc8[i*8+h] = vs; adst8[i*8+h] = vd; }
  }
}

// fused softmax + gather, ONE edge pass. Chunked: lane t computes the 5 alphas
// for edge base+t ONCE into LDS (exp not replicated across lanes), then all 64
// lanes accumulate features with broadcast LDS reads. fp32 alphas; max-free
// softmax (scores bounded << 88); denominator = sum of the same numerators.
__global__ void k_gat_fused(const u16* h2, const int* off, const u16* col,
                            const float* asrc8, const float* adst8,
                            u16* agg5){
  __shared__ float sal[64][6];   // [edge-in-chunk][head], stride 6 floats
  int i = blockIdx.x, t = threadIdx.x;   // 64
  float2 svv = bf2f2(((const u32*)(h2 + (size_t)i*128))[t]);
  float ad[5], dn[5], ax[5], ay[5];
  #pragma unroll
  for (int h = 0; h < 5; ++h){
    ad[h] = adst8[i*8+h];
    float v = asrc8[i*8+h] + ad[h];
    v = (v > 0.f) ? v : 0.2f*v;
    float esf = expf(v);               // self-loop numerator
    dn[h] = esf;
    ax[h] = esf*svv.x; ay[h] = esf*svv.y;
  }
  int lo = off[i], hi = off[i+1];
  for (int base = lo; base < hi; base += 64){
    int n = min(64, hi - base);
    if (t < n){
      int s = col[base + t];
      float4 a03 = *(const float4*)(asrc8 + (size_t)s*8);
      float  a4  = asrc8[(size_t)s*8 + 4];
      float sa[5] = {a03.x, a03.y, a03.z, a03.w, a4};
      #pragma unroll
      for (int h = 0; h < 5; ++h){
        float v = sa[h] + ad[h];
        v = (v > 0.f) ? v : 0.2f*v;
        sal[t][h] = expf(v);
      }
    }
    __syncthreads();
    for (int j = 0; j < n; ++j){
      int s = col[base + j];
      float2 rv = bf2f2(((const u32*)(h2 + (size_t)s*128))[t]);
      #pragma unroll
      for (int h = 0; h < 5; ++h){
        float al = sal[j][h];          // same-address broadcast
        dn[h] += al;
        ax[h] += al*rv.x;
        ay[h] += al*rv.y;
      }
    }
    __syncthreads();
  }
  // dn accumulated identically in every lane (broadcast adds) -> no reduce needed,
  // but it was added n times per lane... NO: each lane adds each alpha exactly once.
  #pragma unroll
  for (int h = 0; h < 5; ++h){
    float iv = 1.f/fmaxf(dn[h]*(1.f/1.f), 1e-16f);
    ((u32*)(agg5 + (size_t)i*640 + h*128))[t] = pack_bf2(ax[h]*iv, ay[h]*iv);
  }
}

// ---------------- fused graph-LN stats + mean pool (single pass over A512) -------
__global__ void k_gstart(const int* batch, int* gs){
  int g = threadIdx.x;
  if (g > NG) return;
  int lo = 0, hi = NN;
  while (lo < hi){ int mid = (lo+hi) >> 1; if (batch[mid] < g) lo = mid+1; else hi = mid; }
  gs[g] = lo;
}
// grid (NG, SPL) x 512 threads: 128 f-threads (ushort4) x 4 row lanes
__global__ void k_poolstat(const u16* a512, const float* ss, const int* gs,
                           float* poolpart, float* sqpart){
  __shared__ float4 red4[512];
  __shared__ float redq[512];
  int g = blockIdx.x, sp = blockIdx.y, t = threadIdx.x;
  int ft = t & 127, rl = t >> 7;
  int f0 = ft*4;
  int lo = gs[g], hi = gs[g+1];
  float sc0 = ss[f0],     sc1 = ss[f0+1],     sc2 = ss[f0+2],     sc3 = ss[f0+3];
  float sh0 = ss[512+f0], sh1 = ss[512+f0+1], sh2 = ss[512+f0+2], sh3 = ss[512+f0+3];
  float4 s4 = {0.f,0.f,0.f,0.f};
  float q = 0.f;
  for (int r = lo + sp*4 + rl; r < hi; r += SPL*4){
    ushort4 u = *(const ushort4*)(a512 + (size_t)r*512 + f0);
    float v0 = gelu_f(bf2f(u.x)*sc0 + sh0);
    float v1 = gelu_f(bf2f(u.y)*sc1 + sh1);
    float v2 = gelu_f(bf2f(u.z)*sc2 + sh2);
    float v3 = gelu_f(bf2f(u.w)*sc3 + sh3);
    s4.x += v0; s4.y += v1; s4.z += v2; s4.w += v3;
    q += v0*v0 + v1*v1 + v2*v2 + v3*v3;
  }
  red4[t] = s4; redq[t] = q;
  __syncthreads();
  for (int st = 256; st; st >>= 1){
    if (t < st) redq[t] += redq[t+st];
    __syncthreads();
  }
  if (t == 0) sqpart[g*SPL + sp] = redq[0];
  if (rl == 0){
    float4 a = red4[t], b = red4[t+128], c = red4[t+256], d = red4[t+384];
    float4 o;
    o.x = a.x+b.x+c.x+d.x; o.y = a.y+b.y+c.y+d.y;
    o.z = a.z+b.z+c.z+d.z; o.w = a.w+b.w+c.w+d.w;
    ((float4*)poolpart)[((size_t)(g*SPL + sp))*128 + ft] = o;
  }
}
// stage A: PRB blocks x 256 threads, deterministic block partials
__global__ void k_poolredA(const float* poolpart, const float* sqpart,
                           float* ppred, float* sqred){
  __shared__ float rs_[256], rq_[256];
  int b = blockIdx.x, t = threadIdx.x;
  float s = 0.f, q = 0.f;
  const int tot = NG*SPL*512;
  for (int i = b*256 + t; i < tot; i += PRB*256) s += poolpart[i];
  for (int i = b*256 + t; i < NG*SPL; i += PRB*256) q += sqpart[i];
  rs_[t] = s; rq_[t] = q;
  __syncthreads();
  for (int st = 128; st; st >>= 1){
    if (t < st){ rs_[t] += rs_[t+st]; rq_[t] += rq_[t+st]; }
    __syncthreads();
  }
  if (t == 0){ ppred[b] = rs_[0]; sqred[b] = rq_[0]; }
}
__global__ void k_poolredB(const float* ppred, const float* sqred, float* scal){
  __shared__ float rs_[128], rq_[128];
  int t = threadIdx.x;   // 128 = PRB
  rs_[t] = ppred[t]; rq_[t] = sqred[t];
  __syncthreads();
  for (int st = 64; st; st >>= 1){
    if (t < st){ rs_[t] += rs_[t+st]; rq_[t] += rq_[t+st]; }
    __syncthreads();
  }
  if (t == 0){
    float invn = 1.f/((float)NN*512.f);
    float mu  = rs_[0]*invn;
    float var = rq_[0]*invn - mu*mu;
    scal[2] = mu;
    scal[3] = rsqrtf(var + EPSV);
  }
}
__global__ void k_poolapply(const float* poolpart, const int* gs, const float* scal,
                            const float* gam, const float* bet, float* pooled){
  int g = blockIdx.x, f = threadIdx.x;   // 512
  float s = 0.f;
  #pragma unroll
  for (int sp = 0; sp < SPL; ++sp)
    s += poolpart[((size_t)(g*SPL + sp))*512 + f];
  float cnt = (float)max(gs[g+1] - gs[g], 1);
  pooled[g*512 + f] = (s/cnt - scal[2])*scal[3]*gam[f] + bet[f];
}

// ---------------- projection head + classifier (fp32, tiny) ----------------
__global__ void k_head_mm1(const float* pooled, const float* w, const float* b, float* q){
  int g = blockIdx.x, j = threadIdx.x;   // 128
  float s = b[j];
  const float* pr = pooled + g*512;
  for (int k = 0; k < 512; ++k) s += pr[k]*w[k*128+j];
  q[g*128+j] = s;
}
__global__ void k_head_bn(const float* qin, const float* g_, const float* be_, float* qout){
  int f = threadIdx.x;   // 128, single block
  float s = 0.f, sq = 0.f;
  for (int r = 0; r < NG; ++r){ float v = qin[r*128+f]; s += v; sq += v*v; }
  float mu = s*(1.f/NG), var = sq*(1.f/NG) - mu*mu;
  float sc = g_[f]*rsqrtf(var + EPSV);
  float sh = be_[f] - mu*sc;
  for (int r = 0; r < NG; ++r) qout[r*128+f] = gelu_f(qin[r*128+f]*sc + sh);
}
// head2 (mm + res + LN + L2-normalize) fused with classifier (log-softmax)
__global__ void k_head2c(const float* q2, const float* w, const float* b,
                         const float* gam, const float* bet,
                         const float* wc, const float* bc, float* out){
  int g = blockIdx.x, j = threadIdx.x;   // 128
  __shared__ float row[128], red[128], shv[3];
  row[j] = q2[g*128+j];
  __syncthreads();
  float s = b[j] + row[j];
  for (int k = 0; k < 128; ++k) s += row[k]*w[k*128+j];
  red[j] = s; __syncthreads();
  for (int st = 64; st; st >>= 1){ if (j < st) red[j] += red[j+st]; __syncthreads(); }
  if (j == 0) shv[0] = red[0]*(1.f/128.f);
  __syncthreads();
  float d = s - shv[0];
  red[j] = d*d; __syncthreads();
  for (int st = 64; st; st >>= 1){ if (j < st) red[j] += red[j+st]; __syncthreads(); }
  if (j == 0) shv[1] = rsqrtf(red[0]*(1.f/128.f) + EPSV);
  __syncthreads();
  float v = d*shv[1]*gam[j] + bet[j];
  red[j] = v*v; __syncthreads();
  for (int st = 64; st; st >>= 1){ if (j < st) red[j] += red[j+st]; __syncthreads(); }
  if (j == 0) shv[2] = 1.f/fmaxf(sqrtf(red[0]), 1e-12f);
  __syncthreads();
  float o = v*shv[2];
  out[g*128+j] = o;
  __syncthreads();
  row[j] = o;        // x1 row for classifier
  __syncthreads();
  float cs = -1e30f;
  if (j < NC){
    cs = bc[j];
    for (int k = 0; k < 128; ++k) cs += row[k]*wc[k*NC+j];
  }
  red[j] = cs; __syncthreads();
  for (int st = 64; st; st >>= 1){ if (j < st) red[j] = fmaxf(red[j], red[j+st]); __syncthreads(); }
  if (j == 0) shv[0] = red[0];
  __syncthreads();
  float e = (j < NC) ? expf(cs - shv[0]) : 0.f;
  red[j] = e; __syncthreads();
  for (int st = 64; st; st >>= 1){ if (j < st) red[j] += red[j+st]; __syncthreads(); }
  if (j == 0) shv[1] = logf(red[0]);
  __syncthreads();
  if (j < NC) out[NG*128 + g*NC+j] = cs - shv[0] - shv[1];
}

extern "C" void kernel_launch(void* const* d_in, const int* in_sizes, int n_in,
                              void* d_out, int out_size, void* d_ws, size_t ws_size,
                              hipStream_t stream){
  const float* x      = (const float*)d_in[0];
  const int*   ei     = (const int*)d_in[1];
  const int*   batch  = (const int*)d_in[2];
  const float* w_in   = (const float*)d_in[3];
  const float* b_in   = (const float*)d_in[4];
  const float* g_in   = (const float*)d_in[5];
  const float* be_in  = (const float*)d_in[6];
  const float* w_h    = (const float*)d_in[7];
  const float* b_h    = (const float*)d_in[8];
  const float* g_h    = (const float*)d_in[9];
  const float* be_h   = (const float*)d_in[10];
  const float* w_gat  = (const float*)d_in[11];
  const float* att_s  = (const float*)d_in[12];
  const float* att_d  = (const float*)d_in[13];
  const float* b_gat  = (const float*)d_in[14];
  const float* w_out  = (const float*)d_in[15];
  const float* b_out  = (const float*)d_in[16];
  const float* g_out  = (const float*)d_in[17];
  const float* be_out = (const float*)d_in[18];
  const float* g_ln   = (const float*)d_in[19];
  const float* be_ln  = (const float*)d_in[20];
  const float* w_p1   = (const float*)d_in[21];
  const float* b_p1   = (const float*)d_in[22];
  const float* g_pbn  = (const float*)d_in[23];
  const float* be_pbn = (const float*)d_in[24];
  const float* w_p2   = (const float*)d_in[25];
  const float* b_p2   = (const float*)d_in[26];
  const float* g_pln  = (const float*)d_in[27];
  const float* be_pln = (const float*)d_in[28];
  const float* w_c    = (const float*)d_in[29];
  const float* b_c    = (const float*)d_in[30];
  float* out = (float*)d_out;

  char* ws = (char*)d_ws;
  size_t o = 0;
  auto carve = [&](size_t bytes) -> char* {
    char* p = ws + o;
    o += (bytes + 255) & ~(size_t)255;
    return p;
  };
  int*   deg    = (int*)  carve((size_t)NN*4);
  int*   off    = (int*)  carve((size_t)(NN+1)*4);
  int*   cur    = (int*)  carve((size_t)NN*4);
  u16*   col    = (u16*)  carve((size_t)NE*2);       // 1.6 MB (u16 node ids)
  float* dis    = (float*)carve((size_t)NN*4);
  int*   bsum   = (int*)  carve((size_t)SCB*4);
  int*   boff   = (int*)  carve((size_t)(SCB+1)*4);
  float* aggx3  = (float*)carve((size_t)NN*3*4);
  u16*   F0     = (u16*)  carve((size_t)NN*128*2);   // 12.8 MB
  u16*   F1     = (u16*)  carve((size_t)NN*128*2);
  u16*   F2     = (u16*)  carve((size_t)NN*128*2);
  u16*   AGG5   = (u16*)  carve((size_t)NN*640*2);   // 64 MB; later aliased as A512
  float* asrc8  = (float*)carve((size_t)NN*8*4);     // 1.6 MB stride-8
  float* adst8  = (float*)carve((size_t)NN*8*4);
  float* wvs    = (float*)carve(640*4);
  float* wvd    = (float*)carve(640*4);
  u16*   BfH    = (u16*)  carve((size_t)128*128*2);
  u16*   BfG    = (u16*)  carve((size_t)640*128*2);
  u16*   BfO    = (u16*)  carve((size_t)128*512*2);
  float* part   = (float*)carve((size_t)512*2*PBN*4);   // 1 MB, feature-major
  float* poolpart = (float*)carve((size_t)NG*SPL*512*4); // 1 MB
  float* sqpart = (float*)carve((size_t)NG*SPL*4);
  float* ppred  = (float*)carve((size_t)PRB*4);
  float* sqred  = (float*)carve((size_t)PRB*4);
  float* ssbuf  = (float*)carve(1024*4);
  float* scal   = (float*)carve(64);
  int*   gst    = (int*)  carve(65*4);
  float* pooled = (float*)carve((size_t)NG*512*4);
  float* q      = (float*)carve((size_t)NG*128*4);
  float* q2     = (float*)carve((size_t)NG*128*4);
  if (o > ws_size) return;   // ~117 MB total

  u16* A512 = AGG5;        // [NN,512] bf16 reuses AGG5 (dead by then)

  // ---- CSR build ----
  k_deg_init<<<196,256,0,stream>>>(deg);
  k_deg_hist<<<3125,256,0,stream>>>(ei, deg);
  k_scanA<<<SCB,256,0,stream>>>(deg, bsum, dis);
  k_scanB<<<1,256,0,stream>>>(bsum, boff);
  k_scanC<<<SCB,256,0,stream>>>(deg, boff, off, cur);
  k_scatter<<<3125,256,0,stream>>>(ei, cur, col);

  // ---- weight fragment pre-conversion (tiny, one-time) ----
  k_prepB<<<64,256,0,stream>>>(w_h, 128, 128, 1, BfH);
  k_prepBG<<<320,256,0,stream>>>(w_gat, BfG);
  k_prepB<<<256,256,0,stream>>>(w_out, 512, 128, 4, BfO);

  // ---- GCN1: agg in 3-dim, mm 3->128, BN, gelu ----
  k_agg3<<<196,256,0,stream>>>(x, off, col, dis, aggx3);
  k_mm_in<<<(NN*64+255)/256,256,0,stream>>>(aggx3, w_in, b_in, (u32*)F0);   // pre1=F0
  k_bn_part<<<dim3(1,PBN),256,0,stream>>>(F0, 128, 128, part);
  k_bn_fin<<<128,256,0,stream>>>(part, g_in, be_in, ssbuf, 128, 1.f/NN);
  k_bn_apply<false><<<2048,256,0,stream>>>((u32*)F0, ssbuf, nullptr, (u32*)F1); // h1=F1

  // ---- GCN2: agg(h1), mm 128->128 +b, BN, gelu, +res ----
  k_gcn_agg64<<<NN,64,0,stream>>>(F1, off, col, dis, F0);                   // aggH1=F0
  k_mm_mfma<<<dim3(782,1),256,0,stream>>>(F0, 128, NN, 128, BfH, F2, 128, b_h); // pre2=F2
  k_bn_part<<<dim3(1,PBN),256,0,stream>>>(F2, 128, 128, part);
  k_bn_fin<<<128,256,0,stream>>>(part, g_h, be_h, ssbuf, 128, 1.f/NN);
  k_bn_apply<true><<<2048,256,0,stream>>>((u32*)F2, ssbuf, (u32*)F1, (u32*)F0);  // h2=F0

  // ---- GAT: scores from h2, ONE fused softmax+gather edge pass, mm K=640 ----
  k_wv<<<5,128,0,stream>>>(w_gat, att_s, att_d, wvs, wvd);
  k_score10<<<NN,64,0,stream>>>(F0, wvs, wvd, asrc8, adst8);
  k_gat_fused<<<NN,64,0,stream>>>(F0, off, col, asrc8, adst8, AGG5);
  k_mm_mfma<<<dim3(782,1),256,0,stream>>>(AGG5, 640, NN, 640, BfG, F1, 128, b_gat); // h3=F1

  // ---- GCN3: agg(h3), mm 128->512 +b (one dispatch, 4 col chunks) ----
  k_gcn_agg64<<<NN,64,0,stream>>>(F1, off, col, dis, F2);                   // aggH3=F2
  k_mm_mfma<<<dim3(782,4),256,0,stream>>>(F2, 128, NN, 128, BfO, A512, 512, b_out); // pre4=A512
  k_bn_part<<<dim3(4,PBN),256,0,stream>>>(A512, 512, 512, part);
  k_bn_fin<<<512,256,0,stream>>>(part, g_out, be_out, ssbuf, 512, 1.f/NN);

  // ---- fused graph-LN stats + mean pool (single pass; h4 never materialized) ----
  k_gstart<<<1,128,0,stream>>>(batch, gst);
  k_poolstat<<<dim3(NG,SPL),512,0,stream>>>(A512, ssbuf, gst, poolpart, sqpart);
  k_poolredA<<<PRB,256,0,stream>>>(poolpart, sqpart, ppred, sqred);
  k_poolredB<<<1,128,0,stream>>>(ppred, sqred, scal);
  k_poolapply<<<NG,512,0,stream>>>(poolpart, gst, scal, g_ln, be_ln, pooled);

  // ---- projection head + classifier ----
  k_head_mm1<<<NG,128,0,stream>>>(pooled, w_p1, b_p1, q);
  k_head_bn<<<1,128,0,stream>>>(q, g_pbn, be_pbn, q2);
  k_head2c<<<NG,128,0,stream>>>(q2, w_p2, b_p2, g_pln, be_pln, w_c, b_c, out);
}

// Round 13
// 607.490 us; speedup vs baseline: 1.1667x; 1.0102x over previous
//
#include <hip/hip_runtime.h>
#include <hip/hip_bf16.h>
#include <math.h>

#define NN 50000
#define NE 800000
#define NG 64
#define NC 100
#define EPSV 1e-5f
#define PBN 256   // BN partial-sum slots (deterministic, no atomics)
#define SCB 196   // scan blocks (196*256 >= NN)
#define SPL 8     // pool splits per graph
#define PRB 128   // poolred stage-A blocks
#define MMB 782   // mm_mfma row-blocks

typedef unsigned int   u32;
typedef unsigned short u16;
typedef __attribute__((ext_vector_type(8))) short bf16x8;
typedef __attribute__((ext_vector_type(4))) float f32x4;

__device__ __forceinline__ float gelu_f(float x){
  return 0.5f*x*(1.0f + erff(x*0.70710678118654752f));
}
__device__ __forceinline__ float bf2f(u16 u){
  return __uint_as_float(((u32)u)<<16);
}
__device__ __forceinline__ float2 bf2f2(u32 u){
  float2 r;
  r.x = __uint_as_float(u<<16);
  r.y = __uint_as_float(u & 0xffff0000u);
  return r;
}
__device__ __forceinline__ u16 f2bf(float f){
  __hip_bfloat16 h = __float2bfloat16(f);
  return *(u16*)&h;
}
__device__ __forceinline__ u32 pack_bf2(float a, float b){
  return (u32)f2bf(a) | ((u32)f2bf(b)<<16);
}

// ---------------- CSR construction ----------------
__global__ void k_deg_init(int* deg){
  int i = blockIdx.x*256 + threadIdx.x;
  if (i < NN) deg[i] = 1;           // self loop
}
__global__ void k_deg_hist(const int* ei, int* deg){
  int e = blockIdx.x*256 + threadIdx.x;
  if (e < NE) atomicAdd(&deg[ei[NE + e]], 1);   // dst row
}
// partial sums of (deg-1) + dis = rsqrt(deg), fused
__global__ void k_scanA(const int* deg, int* bsum, float* dis){
  __shared__ int red[256];
  int b = blockIdx.x, t = threadIdx.x;
  int i = b*256 + t;
  int d = (i < NN) ? deg[i] : 1;
  if (i < NN) dis[i] = rsqrtf((float)d);
  red[t] = (i < NN) ? d-1 : 0;
  __syncthreads();
  for (int st = 128; st; st >>= 1){
    if (t < st) red[t] += red[t+st];
    __syncthreads();
  }
  if (t == 0) bsum[b] = red[0];
}
__global__ void k_scanB(const int* bsum, int* boff){
  __shared__ int sh[256];
  int t = threadIdx.x;
  sh[t] = (t < SCB) ? bsum[t] : 0;
  __syncthreads();
  for (int d = 1; d < 256; d <<= 1){
    int v = (t >= d) ? sh[t-d] : 0;
    __syncthreads();
    sh[t] += v;
    __syncthreads();
  }
  if (t == 0) boff[0] = 0;
  if (t < SCB) boff[t+1] = sh[t];
}
__global__ void k_scanC(const int* deg, const int* boff, int* off, int* cur){
  __shared__ int sh[256];
  int b = blockIdx.x, t = threadIdx.x;
  int i = b*256 + t;
  int v = (i < NN) ? deg[i]-1 : 0;
  sh[t] = v;
  __syncthreads();
  for (int d = 1; d < 256; d <<= 1){
    int u = (t >= d) ? sh[t-d] : 0;
    __syncthreads();
    sh[t] += u;
    __syncthreads();
  }
  if (i < NN){
    int excl = boff[b] + sh[t] - v;
    off[i] = excl; cur[i] = excl;
    if (i == NN-1) off[NN] = boff[b] + sh[t];
  }
}
__global__ void k_scatter(const int* ei, int* cur, u16* col){
  int e = blockIdx.x*256 + threadIdx.x;
  if (e < NE){
    int s = ei[e], d = ei[NE + e];
    int p = atomicAdd(&cur[d], 1);
    col[p] = (u16)s;
  }
}

// ---------------- GCN1: aggregate in 3-dim input space ----------------
__global__ void k_agg3(const float* x, const int* off, const u16* col,
                       const float* dis, float* aggx){
  int i = blockIdx.x*256 + threadIdx.x;
  if (i >= NN) return;
  float di = dis[i];
  float w0 = di*di;
  float a0 = w0*x[i*3], a1 = w0*x[i*3+1], a2 = w0*x[i*3+2];
  int lo = off[i], hi = off[i+1];
  for (int e = lo; e < hi; ++e){
    int s = col[e];
    float w = dis[s]*di;
    a0 += w*x[s*3]; a1 += w*x[s*3+1]; a2 += w*x[s*3+2];
  }
  aggx[i*3] = a0; aggx[i*3+1] = a1; aggx[i*3+2] = a2;
}

// ---------------- input matmul (K=3) ----------------
__global__ void k_mm_in(const float* aggx, const float* w, const float* bias, u32* outp){
  int gid = blockIdx.x*256 + threadIdx.x;
  if (gid >= NN*64) return;
  int i = gid >> 6, j2 = (gid & 63)*2;
  float a = aggx[i*3]*w[j2]   + aggx[i*3+1]*w[128+j2]   + aggx[i*3+2]*w[256+j2]   + bias[j2];
  float b = aggx[i*3]*w[j2+1] + aggx[i*3+1]*w[128+j2+1] + aggx[i*3+2]*w[256+j2+1] + bias[j2+1];
  outp[gid] = pack_bf2(a, b);
}

// ---------------- B pre-conversion to bf16 fragment-major ----------------
__global__ void k_prepB(const float* B, int ldB, int K, int ncc, u16* Bf){
  int gid = blockIdx.x*256 + threadIdx.x;
  int tot = ncc*K*128;
  if (gid >= tot) return;
  int cc = gid / (K*128);
  int rem = gid - cc*(K*128);
  int k = rem >> 7, n = rem & 127;
  int c128 = k >> 7, kk = k & 127;
  int nt = n >> 4, i = n & 15;
  int ks = kk >> 5, jg = (kk >> 3) & 3, e = kk & 7;
  size_t addr = (size_t)cc*K*128 +
                ((((size_t)(c128*8 + nt)*4 + ks)*4 + jg)*16 + i)*8 + e;
  Bf[addr] = f2bf(B[(size_t)k*ldB + cc*128 + n]);
}
__global__ void k_prepBG(const float* w_gat, u16* Bf){
  int gid = blockIdx.x*256 + threadIdx.x;
  if (gid >= 640*128) return;
  int k = gid >> 7, n = gid & 127;
  int h = k >> 7, kk = k & 127;
  int nt = n >> 4, i = n & 15;
  int ks = kk >> 5, jg = (kk >> 3) & 3, e = kk & 7;
  size_t addr = ((((size_t)(h*8 + nt)*4 + ks)*4 + jg)*16 + i)*8 + e;
  Bf[addr] = f2bf(0.2f * w_gat[(size_t)kk*640 + h*128 + n]);
}

// ---------------- MFMA matmul (coalesced C store; optional fused BN partials) ----
// bnpart layout (if non-null): bnpart[(cOut+f)*2*gridDim.x + bx] = colsum,
//                              [... + gridDim.x + bx] = colsumsq  (over valid rows)
__global__ __launch_bounds__(256) void k_mm_mfma(const u16* A, int lda, int M, int K,
                        const u16* Bf, u16* C, int ldC, const float* bias,
                        float* bnpart){
  __shared__ u16 ct[64*132];
  int tid = threadIdx.x;
  int w = tid >> 6, l = tid & 63;
  int jg = l >> 4, ii = l & 15;
  int m0 = blockIdx.x*64 + w*16;
  int cc = blockIdx.y;
  int arow = m0 + ii; if (arow >= M) arow = M-1;
  const u16* Bfc = Bf + (size_t)cc*K*128;
  f32x4 acc[8] = {};
  for (int c128 = 0; c128 < (K >> 7); ++c128){
    const u16* Ar = A + (size_t)arow*lda + c128*128;
    bf16x8 af[4];
    #pragma unroll
    for (int ks = 0; ks < 4; ++ks)
      af[ks] = *(const bf16x8*)(Ar + ks*32 + jg*8);
    #pragma unroll
    for (int nt = 0; nt < 8; ++nt){
      f32x4 a4 = acc[nt];
      #pragma unroll
      for (int ks = 0; ks < 4; ++ks){
        bf16x8 bfr = *(const bf16x8*)(Bfc +
            ((((size_t)(c128*8 + nt)*4 + ks)*4 + jg)*16 + ii)*8);
        a4 = __builtin_amdgcn_mfma_f32_16x16x32_bf16(af[ks], bfr, a4, 0, 0, 0);
      }
      acc[nt] = a4;
    }
  }
  int cOut = cc*128;
  int lrow0 = w*16 + jg*4;
  #pragma unroll
  for (int nt = 0; nt < 8; ++nt){
    float bv = bias[cOut + nt*16 + ii];
    #pragma unroll
    for (int r = 0; r < 4; ++r)
      ct[(lrow0 + r)*132 + nt*16 + ii] = f2bf(acc[nt][r] + bv);
  }
  __syncthreads();
  int lr0 = tid >> 6;
  int lc = tid & 63;
  #pragma unroll
  for (int rr = 0; rr < 16; ++rr){
    int lrow = rr*4 + lr0;
    int grow = blockIdx.x*64 + lrow;
    if (grow < M)
      *(u32*)(C + (size_t)grow*ldC + cOut + lc*2) = *(const u32*)(ct + lrow*132 + lc*2);
  }
  if (bnpart && tid < 128){
    int rlim = M - blockIdx.x*64; if (rlim > 64) rlim = 64;
    float s = 0.f, q = 0.f;
    for (int r = 0; r < rlim; ++r){
      float v = bf2f(ct[r*132 + tid]);
      s += v; q += v*v;
    }
    size_t fb = (size_t)(cOut + tid)*2*gridDim.x;
    bnpart[fb + blockIdx.x] = s;
    bnpart[fb + gridDim.x + blockIdx.x] = q;
  }
}

// ---------------- GCN aggregate in 128-dim ----------------
__global__ void k_gcn_agg64(const u16* xw, const int* off, const u16* col,
                            const float* dis, u16* out){
  int i = blockIdx.x, t = threadIdx.x;   // 64 threads
  float di = dis[i];
  float2 sv = bf2f2(((const u32*)(xw + (size_t)i*128))[t]);
  float w0 = di*di;
  float ax = w0*sv.x, ay = w0*sv.y;
  int lo = off[i], hi = off[i+1];
  int e = lo;
  for (; e + 4 <= hi; e += 4){
    int s0 = col[e], s1 = col[e+1], s2 = col[e+2], s3 = col[e+3];
    float wA = dis[s0]*di, wB = dis[s1]*di, wC = dis[s2]*di, wD = dis[s3]*di;
    float2 r0 = bf2f2(((const u32*)(xw + (size_t)s0*128))[t]);
    float2 r1 = bf2f2(((const u32*)(xw + (size_t)s1*128))[t]);
    float2 r2 = bf2f2(((const u32*)(xw + (size_t)s2*128))[t]);
    float2 r3 = bf2f2(((const u32*)(xw + (size_t)s3*128))[t]);
    ax += wA*r0.x; ay += wA*r0.y;
    ax += wB*r1.x; ay += wB*r1.y;
    ax += wC*r2.x; ay += wC*r2.y;
    ax += wD*r3.x; ay += wD*r3.y;
  }
  for (; e < hi; ++e){
    int s = col[e];
    float w = dis[s]*di;
    float2 rv = bf2f2(((const u32*)(xw + (size_t)s*128))[t]);
    ax += w*rv.x; ay += w*rv.y;
  }
  ((u32*)(out + (size_t)i*128))[t] = pack_bf2(ax, ay);
}

// ---------------- BatchNorm (GCN1 path: vectorized partials, feature-major) -----
__global__ void k_bn_part(const u16* x, int stride, int W, float* part){
  __shared__ float shs[8][132];
  __shared__ float shq[8][132];
  int t = threadIdx.x;
  int ft = t & 31, rl = t >> 5;
  int f0 = ft*4;
  int fbase = blockIdx.x*128;
  int p = blockIdx.y;
  float s0=0.f,s1=0.f,s2=0.f,s3=0.f, q0=0.f,q1=0.f,q2=0.f,q3=0.f;
  for (int r = p + PBN*rl; r < NN; r += PBN*8){
    ushort4 u = *(const ushort4*)(x + (size_t)r*stride + fbase + f0);
    float v0 = bf2f(u.x), v1 = bf2f(u.y), v2 = bf2f(u.z), v3 = bf2f(u.w);
    s0 += v0; s1 += v1; s2 += v2; s3 += v3;
    q0 += v0*v0; q1 += v1*v1; q2 += v2*v2; q3 += v3*v3;
  }
  shs[rl][f0] = s0; shs[rl][f0+1] = s1; shs[rl][f0+2] = s2; shs[rl][f0+3] = s3;
  shq[rl][f0] = q0; shq[rl][f0+1] = q1; shq[rl][f0+2] = q2; shq[rl][f0+3] = q3;
  __syncthreads();
  if (t < 128){
    float s = 0.f, q = 0.f;
    #pragma unroll
    for (int r = 0; r < 8; ++r){ s += shs[r][t]; q += shq[r][t]; }
    size_t fb = (size_t)(fbase + t)*2*PBN;
    part[fb + p] = s;
    part[fb + PBN + p] = q;
  }
}
__global__ void k_bn_fin(const float* part, const float* g, const float* be,
                         float* ss, int W, float invn){
  __shared__ float rs[256], rq[256];
  int f = blockIdx.x, t = threadIdx.x;
  size_t fb = (size_t)f*2*PBN;
  rs[t] = part[fb + t];
  rq[t] = part[fb + PBN + t];
  __syncthreads();
  for (int st = 128; st; st >>= 1){
    if (t < st){ rs[t] += rs[t+st]; rq[t] += rq[t+st]; }
    __syncthreads();
  }
  if (t == 0){
    float mean = rs[0]*invn;
    float var  = rq[0]*invn - mean*mean;
    float sc = g[f]*rsqrtf(var + EPSV);
    ss[f] = sc;
    ss[W+f] = be[f] - mean*sc;
  }
}
// finisher for mm-fused partials (NB slots, feature-major)
__global__ void k_bn_finB(const float* part, int NB, const float* g, const float* be,
                          float* ss, int W, float invn){
  __shared__ float rs[256], rq[256];
  int f = blockIdx.x, t = threadIdx.x;
  size_t fb = (size_t)f*2*NB;
  float s = 0.f, q = 0.f;
  for (int b = t; b < NB; b += 256){ s += part[fb + b]; q += part[fb + NB + b]; }
  rs[t] = s; rq[t] = q;
  __syncthreads();
  for (int st = 128; st; st >>= 1){
    if (t < st){ rs[t] += rs[t+st]; rq[t] += rq[t+st]; }
    __syncthreads();
  }
  if (t == 0){
    float mean = rs[0]*invn;
    float var  = rq[0]*invn - mean*mean;
    float sc = g[f]*rsqrtf(var + EPSV);
    ss[f] = sc;
    ss[W+f] = be[f] - mean*sc;
  }
}
template<bool RES>
__global__ void k_bn_apply(const u32* x, const float* ss, const u32* res, u32* out){
  const int n = NN*64;
  for (int idx = blockIdx.x*256 + threadIdx.x; idx < n; idx += gridDim.x*256){
    int f2 = (idx & 63)*2;
    float2 v = bf2f2(x[idx]);
    v.x = gelu_f(v.x*ss[f2]   + ss[128+f2]);
    v.y = gelu_f(v.y*ss[f2+1] + ss[128+f2+1]);
    if (RES){ float2 r = bf2f2(res[idx]); v.x += r.x; v.y += r.y; }
    out[idx] = pack_bf2(v.x, v.y);
  }
}

// ---------------- GAT ----------------
__global__ void k_wv(const float* w_gat, const float* att_s, const float* att_d,
                     float* wvs, float* wvd){
  int h = blockIdx.x, c = threadIdx.x;   // 5 blocks x 128
  float ss = 0.f, sd = 0.f;
  const float* wr = w_gat + (size_t)c*640 + h*128;
  const float* as = att_s + h*128;
  const float* ad = att_d + h*128;
  for (int k = 0; k < 128; ++k){
    float wv = wr[k];
    ss += wv*as[k]; sd += wv*ad[k];
  }
  wvs[h*128+c] = ss; wvd[h*128+c] = sd;
}

// per-node scores; stride-8 output so per-edge loads are one aligned float4+float
__global__ void k_score10(const u16* h2, const float* wvs, const float* wvd,
                          float* asrc8, float* adst8){
  int i = blockIdx.x, t = threadIdx.x;   // 64
  float2 v = bf2f2(((const u32*)(h2 + (size_t)i*128))[t]);
  int f2 = 2*t;
  #pragma unroll
  for (int h = 0; h < 5; ++h){
    float vs = v.x*wvs[h*128+f2] + v.y*wvs[h*128+f2+1];
    float vd = v.x*wvd[h*128+f2] + v.y*wvd[h*128+f2+1];
    #pragma unroll
    for (int d = 32; d; d >>= 1){ vs += __shfl_xor(vs, d); vd += __shfl_xor(vd, d); }
    if (t == 0){ asrc8[i*8+h] = vs; adst8[i*8+h] = vd; }
  }
}

// fused softmax + gather, ONE edge pass, chunked.
// Phase 1: lane t computes the 5 alphas for edge base+t ONCE (exp not replicated),
//          stores alphas + col to LDS, accumulates its own dn contribution.
// Phase 2: all 64 lanes accumulate features with broadcast LDS reads (no dn work).
// End: wave-reduce dn, add self numerator, normalize. fp32 alphas; max-free
// softmax (scores bounded << 88).
__global__ void k_gat_fused(const u16* h2, const int* off, const u16* col,
                            const float* asrc8, const float* adst8,
                            u16* agg5){
  __shared__ float sal[64][6];   // [edge-in-chunk][head]
  __shared__ int   scol[64];
  int i = blockIdx.x, t = threadIdx.x;   // 64
  float2 svv = bf2f2(((const u32*)(h2 + (size_t)i*128))[t]);
  float ad[5], dn[5], ax[5], ay[5];
  float esf[5];
  #pragma unroll
  for (int h = 0; h < 5; ++h){
    ad[h] = adst8[i*8+h];
    float v = asrc8[i*8+h] + ad[h];
    v = (v > 0.f) ? v : 0.2f*v;
    esf[h] = expf(v);                  // self-loop numerator (all lanes identical)
    dn[h] = 0.f;
    ax[h] = esf[h]*svv.x; ay[h] = esf[h]*svv.y;
  }
  int lo = off[i], hi = off[i+1];
  for (int base = lo; base < hi; base += 64){
    int n = min(64, hi - base);
    if (t < n){
      int s = col[base + t];
      scol[t] = s;
      float4 a03 = *(const float4*)(asrc8 + (size_t)s*8);
      float  a4  = asrc8[(size_t)s*8 + 4];
      float sa[5] = {a03.x, a03.y, a03.z, a03.w, a4};
      #pragma unroll
      for (int h = 0; h < 5; ++h){
        float v = sa[h] + ad[h];
        v = (v > 0.f) ? v : 0.2f*v;
        float ex = expf(v);
        sal[t][h] = ex;
        dn[h] += ex;                   // owner-lane dn contribution
      }
    }
    __syncthreads();
    for (int j = 0; j < n; ++j){
      int s = scol[j];                 // LDS broadcast
      float2 rv = bf2f2(((const u32*)(h2 + (size_t)s*128))[t]);
      #pragma unroll
      for (int h = 0; h < 5; ++h){
        float al = sal[j][h];          // LDS broadcast
        ax[h] += al*rv.x;
        ay[h] += al*rv.y;
      }
    }
    __syncthreads();
  }
  #pragma unroll
  for (int h = 0; h < 5; ++h){
    #pragma unroll
    for (int d = 32; d; d >>= 1) dn[h] += __shfl_xor(dn[h], d);
    float iv = 1.f/fmaxf(dn[h] + esf[h], 1e-16f);
    ((u32*)(agg5 + (size_t)i*640 + h*128))[t] = pack_bf2(ax[h]*iv, ay[h]*iv);
  }
}

// ---------------- fused graph-LN stats + mean pool (single pass over A512) -------
__global__ void k_gstart(const int* batch, int* gs){
  int g = threadIdx.x;
  if (g > NG) return;
  int lo = 0, hi = NN;
  while (lo < hi){ int mid = (lo+hi) >> 1; if (batch[mid] < g) lo = mid+1; else hi = mid; }
  gs[g] = lo;
}
// grid (NG, SPL) x 512 threads: 128 f-threads (ushort4) x 4 row lanes
__global__ void k_poolstat(const u16* a512, const float* ss, const int* gs,
                           float* poolpart, float* sqpart){
  __shared__ float4 red4[512];
  __shared__ float redq[512];
  int g = blockIdx.x, sp = blockIdx.y, t = threadIdx.x;
  int ft = t & 127, rl = t >> 7;
  int f0 = ft*4;
  int lo = gs[g], hi = gs[g+1];
  float sc0 = ss[f0],     sc1 = ss[f0+1],     sc2 = ss[f0+2],     sc3 = ss[f0+3];
  float sh0 = ss[512+f0], sh1 = ss[512+f0+1], sh2 = ss[512+f0+2], sh3 = ss[512+f0+3];
  float4 s4 = {0.f,0.f,0.f,0.f};
  float q = 0.f;
  for (int r = lo + sp*4 + rl; r < hi; r += SPL*4){
    ushort4 u = *(const ushort4*)(a512 + (size_t)r*512 + f0);
    float v0 = gelu_f(bf2f(u.x)*sc0 + sh0);
    float v1 = gelu_f(bf2f(u.y)*sc1 + sh1);
    float v2 = gelu_f(bf2f(u.z)*sc2 + sh2);
    float v3 = gelu_f(bf2f(u.w)*sc3 + sh3);
    s4.x += v0; s4.y += v1; s4.z += v2; s4.w += v3;
    q += v0*v0 + v1*v1 + v2*v2 + v3*v3;
  }
  red4[t] = s4; redq[t] = q;
  __syncthreads();
  for (int st = 256; st; st >>= 1){
    if (t < st) redq[t] += redq[t+st];
    __syncthreads();
  }
  if (t == 0) sqpart[g*SPL + sp] = redq[0];
  if (rl == 0){
    float4 a = red4[t], b = red4[t+128], c = red4[t+256], d = red4[t+384];
    float4 o;
    o.x = a.x+b.x+c.x+d.x; o.y = a.y+b.y+c.y+d.y;
    o.z = a.z+b.z+c.z+d.z; o.w = a.w+b.w+c.w+d.w;
    ((float4*)poolpart)[((size_t)(g*SPL + sp))*128 + ft] = o;
  }
}
// stage A: PRB blocks x 256 threads, deterministic block partials
__global__ void k_poolredA(const float* poolpart, const float* sqpart,
                           float* ppred, float* sqred){
  __shared__ float rs_[256], rq_[256];
  int b = blockIdx.x, t = threadIdx.x;
  float s = 0.f, q = 0.f;
  const int tot = NG*SPL*512;
  for (int i = b*256 + t; i < tot; i += PRB*256) s += poolpart[i];
  for (int i = b*256 + t; i < NG*SPL; i += PRB*256) q += sqpart[i];
  rs_[t] = s; rq_[t] = q;
  __syncthreads();
  for (int st = 128; st; st >>= 1){
    if (t < st){ rs_[t] += rs_[t+st]; rq_[t] += rq_[t+st]; }
    __syncthreads();
  }
  if (t == 0){ ppred[b] = rs_[0]; sqred[b] = rq_[0]; }
}
__global__ void k_poolredB(const float* ppred, const float* sqred, float* scal){
  __shared__ float rs_[128], rq_[128];
  int t = threadIdx.x;   // 128 = PRB
  rs_[t] = ppred[t]; rq_[t] = sqred[t];
  __syncthreads();
  for (int st = 64; st; st >>= 1){
    if (t < st){ rs_[t] += rs_[t+st]; rq_[t] += rq_[t+st]; }
    __syncthreads();
  }
  if (t == 0){
    float invn = 1.f/((float)NN*512.f);
    float mu  = rs_[0]*invn;
    float var = rq_[0]*invn - mu*mu;
    scal[2] = mu;
    scal[3] = rsqrtf(var + EPSV);
  }
}
__global__ void k_poolapply(const float* poolpart, const int* gs, const float* scal,
                            const float* gam, const float* bet, float* pooled){
  int g = blockIdx.x, f = threadIdx.x;   // 512
  float s = 0.f;
  #pragma unroll
  for (int sp = 0; sp < SPL; ++sp)
    s += poolpart[((size_t)(g*SPL + sp))*512 + f];
  float cnt = (float)max(gs[g+1] - gs[g], 1);
  pooled[g*512 + f] = (s/cnt - scal[2])*scal[3]*gam[f] + bet[f];
}

// ---------------- projection head + classifier (fp32, tiny) ----------------
__global__ void k_head_mm1(const float* pooled, const float* w, const float* b, float* q){
  int g = blockIdx.x, j = threadIdx.x;   // 128
  float s = b[j];
  const float* pr = pooled + g*512;
  for (int k = 0; k < 512; ++k) s += pr[k]*w[k*128+j];
  q[g*128+j] = s;
}
__global__ void k_head_bn(const float* qin, const float* g_, const float* be_, float* qout){
  int f = threadIdx.x;   // 128, single block
  float s = 0.f, sq = 0.f;
  for (int r = 0; r < NG; ++r){ float v = qin[r*128+f]; s += v; sq += v*v; }
  float mu = s*(1.f/NG), var = sq*(1.f/NG) - mu*mu;
  float sc = g_[f]*rsqrtf(var + EPSV);
  float sh = be_[f] - mu*sc;
  for (int r = 0; r < NG; ++r) qout[r*128+f] = gelu_f(qin[r*128+f]*sc + sh);
}
// head2 (mm + res + LN + L2-normalize) fused with classifier (log-softmax)
__global__ void k_head2c(const float* q2, const float* w, const float* b,
                         const float* gam, const float* bet,
                         const float* wc, const float* bc, float* out){
  int g = blockIdx.x, j = threadIdx.x;   // 128
  __shared__ float row[128], red[128], shv[3];
  row[j] = q2[g*128+j];
  __syncthreads();
  float s = b[j] + row[j];
  for (int k = 0; k < 128; ++k) s += row[k]*w[k*128+j];
  red[j] = s; __syncthreads();
  for (int st = 64; st; st >>= 1){ if (j < st) red[j] += red[j+st]; __syncthreads(); }
  if (j == 0) shv[0] = red[0]*(1.f/128.f);
  __syncthreads();
  float d = s - shv[0];
  red[j] = d*d; __syncthreads();
  for (int st = 64; st; st >>= 1){ if (j < st) red[j] += red[j+st]; __syncthreads(); }
  if (j == 0) shv[1] = rsqrtf(red[0]*(1.f/128.f) + EPSV);
  __syncthreads();
  float v = d*shv[1]*gam[j] + bet[j];
  red[j] = v*v; __syncthreads();
  for (int st = 64; st; st >>= 1){ if (j < st) red[j] += red[j+st]; __syncthreads(); }
  if (j == 0) shv[2] = 1.f/fmaxf(sqrtf(red[0]), 1e-12f);
  __syncthreads();
  float o = v*shv[2];
  out[g*128+j] = o;
  __syncthreads();
  row[j] = o;        // x1 row for classifier
  __syncthreads();
  float cs = -1e30f;
  if (j < NC){
    cs = bc[j];
    for (int k = 0; k < 128; ++k) cs += row[k]*wc[k*NC+j];
  }
  red[j] = cs; __syncthreads();
  for (int st = 64; st; st >>= 1){ if (j < st) red[j] = fmaxf(red[j], red[j+st]); __syncthreads(); }
  if (j == 0) shv[0] = red[0];
  __syncthreads();
  float e = (j < NC) ? expf(cs - shv[0]) : 0.f;
  red[j] = e; __syncthreads();
  for (int st = 64; st; st >>= 1){ if (j < st) red[j] += red[j+st]; __syncthreads(); }
  if (j == 0) shv[1] = logf(red[0]);
  __syncthreads();
  if (j < NC) out[NG*128 + g*NC+j] = cs - shv[0] - shv[1];
}

extern "C" void kernel_launch(void* const* d_in, const int* in_sizes, int n_in,
                              void* d_out, int out_size, void* d_ws, size_t ws_size,
                              hipStream_t stream){
  const float* x      = (const float*)d_in[0];
  const int*   ei     = (const int*)d_in[1];
  const int*   batch  = (const int*)d_in[2];
  const float* w_in   = (const float*)d_in[3];
  const float* b_in   = (const float*)d_in[4];
  const float* g_in   = (const float*)d_in[5];
  const float* be_in  = (const float*)d_in[6];
  const float* w_h    = (const float*)d_in[7];
  const float* b_h    = (const float*)d_in[8];
  const float* g_h    = (const float*)d_in[9];
  const float* be_h   = (const float*)d_in[10];
  const float* w_gat  = (const float*)d_in[11];
  const float* att_s  = (const float*)d_in[12];
  const float* att_d  = (const float*)d_in[13];
  const float* b_gat  = (const float*)d_in[14];
  const float* w_out  = (const float*)d_in[15];
  const float* b_out  = (const float*)d_in[16];
  const float* g_out  = (const float*)d_in[17];
  const float* be_out = (const float*)d_in[18];
  const float* g_ln   = (const float*)d_in[19];
  const float* be_ln  = (const float*)d_in[20];
  const float* w_p1   = (const float*)d_in[21];
  const float* b_p1   = (const float*)d_in[22];
  const float* g_pbn  = (const float*)d_in[23];
  const float* be_pbn = (const float*)d_in[24];
  const float* w_p2   = (const float*)d_in[25];
  const float* b_p2   = (const float*)d_in[26];
  const float* g_pln  = (const float*)d_in[27];
  const float* be_pln = (const float*)d_in[28];
  const float* w_c    = (const float*)d_in[29];
  const float* b_c    = (const float*)d_in[30];
  float* out = (float*)d_out;

  char* ws = (char*)d_ws;
  size_t o = 0;
  auto carve = [&](size_t bytes) -> char* {
    char* p = ws + o;
    o += (bytes + 255) & ~(size_t)255;
    return p;
  };
  int*   deg    = (int*)  carve((size_t)NN*4);
  int*   off    = (int*)  carve((size_t)(NN+1)*4);
  int*   cur    = (int*)  carve((size_t)NN*4);
  u16*   col    = (u16*)  carve((size_t)NE*2);       // 1.6 MB (u16 node ids)
  float* dis    = (float*)carve((size_t)NN*4);
  int*   bsum   = (int*)  carve((size_t)SCB*4);
  int*   boff   = (int*)  carve((size_t)(SCB+1)*4);
  float* aggx3  = (float*)carve((size_t)NN*3*4);
  u16*   F0     = (u16*)  carve((size_t)NN*128*2);   // 12.8 MB
  u16*   F1     = (u16*)  carve((size_t)NN*128*2);
  u16*   F2     = (u16*)  carve((size_t)NN*128*2);
  u16*   AGG5   = (u16*)  carve((size_t)NN*640*2);   // 64 MB; later aliased as A512
  float* asrc8  = (float*)carve((size_t)NN*8*4);     // 1.6 MB stride-8
  float* adst8  = (float*)carve((size_t)NN*8*4);
  float* wvs    = (float*)carve(640*4);
  float* wvd    = (float*)carve(640*4);
  u16*   BfH    = (u16*)  carve((size_t)128*128*2);
  u16*   BfG    = (u16*)  carve((size_t)640*128*2);
  u16*   BfO    = (u16*)  carve((size_t)128*512*2);
  float* part   = (float*)carve((size_t)512*2*MMB*4);   // 3.2 MB (feature-major, max slots)
  float* poolpart = (float*)carve((size_t)NG*SPL*512*4); // 1 MB
  float* sqpart = (float*)carve((size_t)NG*SPL*4);
  float* ppred  = (float*)carve((size_t)PRB*4);
  float* sqred  = (float*)carve((size_t)PRB*4);
  float* ssbuf  = (float*)carve(1024*4);
  float* scal   = (float*)carve(64);
  int*   gst    = (int*)  carve(65*4);
  float* pooled = (float*)carve((size_t)NG*512*4);
  float* q      = (float*)carve((size_t)NG*128*4);
  float* q2     = (float*)carve((size_t)NG*128*4);
  if (o > ws_size) return;   // ~119 MB total

  u16* A512 = AGG5;        // [NN,512] bf16 reuses AGG5 (dead by then)

  // ---- CSR build ----
  k_deg_init<<<196,256,0,stream>>>(deg);
  k_deg_hist<<<3125,256,0,stream>>>(ei, deg);
  k_scanA<<<SCB,256,0,stream>>>(deg, bsum, dis);
  k_scanB<<<1,256,0,stream>>>(bsum, boff);
  k_scanC<<<SCB,256,0,stream>>>(deg, boff, off, cur);
  k_scatter<<<3125,256,0,stream>>>(ei, cur, col);

  // ---- weight fragment pre-conversion (tiny, one-time) ----
  k_prepB<<<64,256,0,stream>>>(w_h, 128, 128, 1, BfH);
  k_prepBG<<<320,256,0,stream>>>(w_gat, BfG);
  k_prepB<<<256,256,0,stream>>>(w_out, 512, 128, 4, BfO);

  // ---- GCN1: agg in 3-dim, mm 3->128, BN, gelu ----
  k_agg3<<<196,256,0,stream>>>(x, off, col, dis, aggx3);
  k_mm_in<<<(NN*64+255)/256,256,0,stream>>>(aggx3, w_in, b_in, (u32*)F0);   // pre1=F0
  k_bn_part<<<dim3(1,PBN),256,0,stream>>>(F0, 128, 128, part);
  k_bn_fin<<<128,256,0,stream>>>(part, g_in, be_in, ssbuf, 128, 1.f/NN);
  k_bn_apply<false><<<2048,256,0,stream>>>((u32*)F0, ssbuf, nullptr, (u32*)F1); // h1=F1

  // ---- GCN2: agg(h1), mm 128->128 +b (fused BN stats), BN, gelu, +res ----
  k_gcn_agg64<<<NN,64,0,stream>>>(F1, off, col, dis, F0);                   // aggH1=F0
  k_mm_mfma<<<dim3(MMB,1),256,0,stream>>>(F0, 128, NN, 128, BfH, F2, 128, b_h, part); // pre2=F2
  k_bn_finB<<<128,256,0,stream>>>(part, MMB, g_h, be_h, ssbuf, 128, 1.f/NN);
  k_bn_apply<true><<<2048,256,0,stream>>>((u32*)F2, ssbuf, (u32*)F1, (u32*)F0);  // h2=F0

  // ---- GAT: scores from h2, ONE fused softmax+gather edge pass, mm K=640 ----
  k_wv<<<5,128,0,stream>>>(w_gat, att_s, att_d, wvs, wvd);
  k_score10<<<NN,64,0,stream>>>(F0, wvs, wvd, asrc8, adst8);
  k_gat_fused<<<NN,64,0,stream>>>(F0, off, col, asrc8, adst8, AGG5);
  k_mm_mfma<<<dim3(MMB,1),256,0,stream>>>(AGG5, 640, NN, 640, BfG, F1, 128, b_gat, nullptr); // h3=F1

  // ---- GCN3: agg(h3), mm 128->512 +b (fused BN stats, 4 col chunks) ----
  k_gcn_agg64<<<NN,64,0,stream>>>(F1, off, col, dis, F2);                   // aggH3=F2
  k_mm_mfma<<<dim3(MMB,4),256,0,stream>>>(F2, 128, NN, 128, BfO, A512, 512, b_out, part); // pre4=A512
  k_bn_finB<<<512,256,0,stream>>>(part, MMB, g_out, be_out, ssbuf, 512, 1.f/NN);

  // ---- fused graph-LN stats + mean pool (single pass; h4 never materialized) ----
  k_gstart<<<1,128,0,stream>>>(batch, gst);
  k_poolstat<<<dim3(NG,SPL),512,0,stream>>>(A512, ssbuf, gst, poolpart, sqpart);
  k_poolredA<<<PRB,256,0,stream>>>(poolpart, sqpart, ppred, sqred);
  k_poolredB<<<1,128,0,stream>>>(ppred, sqred, scal);
  k_poolapply<<<NG,512,0,stream>>>(poolpart, gst, scal, g_ln, be_ln, pooled);

  // ---- projection head + classifier ----
  k_head_mm1<<<NG,128,0,stream>>>(pooled, w_p1, b_p1, q);
  k_head_bn<<<1,128,0,stream>>>(q, g_pbn, be_pbn, q2);
  k_head2c<<<NG,128,0,stream>>>(q2, w_p2, b_p2, g_pln, be_pln, w_c, b_c, out);
}

// Round 14
// 605.103 us; speedup vs baseline: 1.1713x; 1.0039x over previous
//
#include <hip/hip_runtime.h>
#include <hip/hip_bf16.h>
#include <math.h>

#define NN 50000
#define NE 800000
#define NG 64
#define NC 100
#define EPSV 1e-5f
#define PBN 256   // BN partial-sum slots (deterministic, no atomics)
#define SCB 196   // scan blocks (196*256 >= NN)
#define SPL 8     // pool splits per graph
#define PRB 128   // poolred stage-A blocks
#define MMB 782   // mm_mfma row-blocks

typedef unsigned int   u32;
typedef unsigned short u16;
typedef __attribute__((ext_vector_type(8))) short bf16x8;
typedef __attribute__((ext_vector_type(4))) float f32x4;

__device__ __forceinline__ float gelu_f(float x){
  return 0.5f*x*(1.0f + erff(x*0.70710678118654752f));
}
__device__ __forceinline__ float bf2f(u16 u){
  return __uint_as_float(((u32)u)<<16);
}
__device__ __forceinline__ float2 bf2f2(u32 u){
  float2 r;
  r.x = __uint_as_float(u<<16);
  r.y = __uint_as_float(u & 0xffff0000u);
  return r;
}
__device__ __forceinline__ u16 f2bf(float f){
  __hip_bfloat16 h = __float2bfloat16(f);
  return *(u16*)&h;
}
__device__ __forceinline__ u32 pack_bf2(float a, float b){
  return (u32)f2bf(a) | ((u32)f2bf(b)<<16);
}

// ---------------- CSR construction ----------------
__global__ void k_deg_init(int* deg){
  int i = blockIdx.x*256 + threadIdx.x;
  if (i < NN) deg[i] = 1;           // self loop
}
__global__ void k_deg_hist(const int* ei, int* deg){
  int e = blockIdx.x*256 + threadIdx.x;
  if (e < NE) atomicAdd(&deg[ei[NE + e]], 1);   // dst row
}
// partial sums of (deg-1) + dis = rsqrt(deg), fused
__global__ void k_scanA(const int* deg, int* bsum, float* dis){
  __shared__ int red[256];
  int b = blockIdx.x, t = threadIdx.x;
  int i = b*256 + t;
  int d = (i < NN) ? deg[i] : 1;
  if (i < NN) dis[i] = rsqrtf((float)d);
  red[t] = (i < NN) ? d-1 : 0;
  __syncthreads();
  for (int st = 128; st; st >>= 1){
    if (t < st) red[t] += red[t+st];
    __syncthreads();
  }
  if (t == 0) bsum[b] = red[0];
}
__global__ void k_scanB(const int* bsum, int* boff){
  __shared__ int sh[256];
  int t = threadIdx.x;
  sh[t] = (t < SCB) ? bsum[t] : 0;
  __syncthreads();
  for (int d = 1; d < 256; d <<= 1){
    int v = (t >= d) ? sh[t-d] : 0;
    __syncthreads();
    sh[t] += v;
    __syncthreads();
  }
  if (t == 0) boff[0] = 0;
  if (t < SCB) boff[t+1] = sh[t];
}
__global__ void k_scanC(const int* deg, const int* boff, int* off, int* cur){
  __shared__ int sh[256];
  int b = blockIdx.x, t = threadIdx.x;
  int i = b*256 + t;
  int v = (i < NN) ? deg[i]-1 : 0;
  sh[t] = v;
  __syncthreads();
  for (int d = 1; d < 256; d <<= 1){
    int u = (t >= d) ? sh[t-d] : 0;
    __syncthreads();
    sh[t] += u;
    __syncthreads();
  }
  if (i < NN){
    int excl = boff[b] + sh[t] - v;
    off[i] = excl; cur[i] = excl;
    if (i == NN-1) off[NN] = boff[b] + sh[t];
  }
}
__global__ void k_scatter(const int* ei, int* cur, u16* col){
  int e = blockIdx.x*256 + threadIdx.x;
  if (e < NE){
    int s = ei[e], d = ei[NE + e];
    int p = atomicAdd(&cur[d], 1);
    col[p] = (u16)s;
  }
}

// ---------------- GCN1: aggregate in 3-dim input space ----------------
__global__ void k_agg3(const float* x, const int* off, const u16* col,
                       const float* dis, float* aggx){
  int i = blockIdx.x*256 + threadIdx.x;
  if (i >= NN) return;
  float di = dis[i];
  float w0 = di*di;
  float a0 = w0*x[i*3], a1 = w0*x[i*3+1], a2 = w0*x[i*3+2];
  int lo = off[i], hi = off[i+1];
  for (int e = lo; e < hi; ++e){
    int s = col[e];
    float w = dis[s]*di;
    a0 += w*x[s*3]; a1 += w*x[s*3+1]; a2 += w*x[s*3+2];
  }
  aggx[i*3] = a0; aggx[i*3+1] = a1; aggx[i*3+2] = a2;
}

// ---------------- input matmul (K=3) ----------------
__global__ void k_mm_in(const float* aggx, const float* w, const float* bias, u32* outp){
  int gid = blockIdx.x*256 + threadIdx.x;
  if (gid >= NN*64) return;
  int i = gid >> 6, j2 = (gid & 63)*2;
  float a = aggx[i*3]*w[j2]   + aggx[i*3+1]*w[128+j2]   + aggx[i*3+2]*w[256+j2]   + bias[j2];
  float b = aggx[i*3]*w[j2+1] + aggx[i*3+1]*w[128+j2+1] + aggx[i*3+2]*w[256+j2+1] + bias[j2+1];
  outp[gid] = pack_bf2(a, b);
}

// ---------------- B pre-conversion to bf16 fragment-major ----------------
__global__ void k_prepB(const float* B, int ldB, int K, int ncc, u16* Bf){
  int gid = blockIdx.x*256 + threadIdx.x;
  int tot = ncc*K*128;
  if (gid >= tot) return;
  int cc = gid / (K*128);
  int rem = gid - cc*(K*128);
  int k = rem >> 7, n = rem & 127;
  int c128 = k >> 7, kk = k & 127;
  int nt = n >> 4, i = n & 15;
  int ks = kk >> 5, jg = (kk >> 3) & 3, e = kk & 7;
  size_t addr = (size_t)cc*K*128 +
                ((((size_t)(c128*8 + nt)*4 + ks)*4 + jg)*16 + i)*8 + e;
  Bf[addr] = f2bf(B[(size_t)k*ldB + cc*128 + n]);
}
__global__ void k_prepBG(const float* w_gat, u16* Bf){
  int gid = blockIdx.x*256 + threadIdx.x;
  if (gid >= 640*128) return;
  int k = gid >> 7, n = gid & 127;
  int h = k >> 7, kk = k & 127;
  int nt = n >> 4, i = n & 15;
  int ks = kk >> 5, jg = (kk >> 3) & 3, e = kk & 7;
  size_t addr = ((((size_t)(h*8 + nt)*4 + ks)*4 + jg)*16 + i)*8 + e;
  Bf[addr] = f2bf(0.2f * w_gat[(size_t)kk*640 + h*128 + n]);
}

// ---------------- MFMA matmul (coalesced C store; optional fused BN partials) ----
__global__ __launch_bounds__(256) void k_mm_mfma(const u16* A, int lda, int M, int K,
                        const u16* Bf, u16* C, int ldC, const float* bias,
                        float* bnpart){
  __shared__ u16 ct[64*132];
  int tid = threadIdx.x;
  int w = tid >> 6, l = tid & 63;
  int jg = l >> 4, ii = l & 15;
  int m0 = blockIdx.x*64 + w*16;
  int cc = blockIdx.y;
  int arow = m0 + ii; if (arow >= M) arow = M-1;
  const u16* Bfc = Bf + (size_t)cc*K*128;
  f32x4 acc[8] = {};
  for (int c128 = 0; c128 < (K >> 7); ++c128){
    const u16* Ar = A + (size_t)arow*lda + c128*128;
    bf16x8 af[4];
    #pragma unroll
    for (int ks = 0; ks < 4; ++ks)
      af[ks] = *(const bf16x8*)(Ar + ks*32 + jg*8);
    #pragma unroll
    for (int nt = 0; nt < 8; ++nt){
      f32x4 a4 = acc[nt];
      #pragma unroll
      for (int ks = 0; ks < 4; ++ks){
        bf16x8 bfr = *(const bf16x8*)(Bfc +
            ((((size_t)(c128*8 + nt)*4 + ks)*4 + jg)*16 + ii)*8);
        a4 = __builtin_amdgcn_mfma_f32_16x16x32_bf16(af[ks], bfr, a4, 0, 0, 0);
      }
      acc[nt] = a4;
    }
  }
  int cOut = cc*128;
  int lrow0 = w*16 + jg*4;
  #pragma unroll
  for (int nt = 0; nt < 8; ++nt){
    float bv = bias[cOut + nt*16 + ii];
    #pragma unroll
    for (int r = 0; r < 4; ++r)
      ct[(lrow0 + r)*132 + nt*16 + ii] = f2bf(acc[nt][r] + bv);
  }
  __syncthreads();
  int lr0 = tid >> 6;
  int lc = tid & 63;
  #pragma unroll
  for (int rr = 0; rr < 16; ++rr){
    int lrow = rr*4 + lr0;
    int grow = blockIdx.x*64 + lrow;
    if (grow < M)
      *(u32*)(C + (size_t)grow*ldC + cOut + lc*2) = *(const u32*)(ct + lrow*132 + lc*2);
  }
  if (bnpart && tid < 128){
    int rlim = M - blockIdx.x*64; if (rlim > 64) rlim = 64;
    float s = 0.f, q = 0.f;
    for (int r = 0; r < rlim; ++r){
      float v = bf2f(ct[r*132 + tid]);
      s += v; q += v*v;
    }
    size_t fb = (size_t)(cOut + tid)*2*gridDim.x;
    bnpart[fb + blockIdx.x] = s;
    bnpart[fb + gridDim.x + blockIdx.x] = q;
  }
}

// ---------------- GCN aggregate in 128-dim (ushort4 col loads) ----------------
__global__ void k_gcn_agg64(const u16* xw, const int* off, const u16* col,
                            const float* dis, u16* out){
  int i = blockIdx.x, t = threadIdx.x;   // 64 threads
  float di = dis[i];
  float2 sv = bf2f2(((const u32*)(xw + (size_t)i*128))[t]);
  float w0 = di*di;
  float ax = w0*sv.x, ay = w0*sv.y;
  int lo = off[i], hi = off[i+1];
  int e = lo;
  // align to 4-edge boundary so ushort4 loads are 8B-aligned
  for (; e < hi && (e & 3); ++e){
    int s = col[e];
    float w = dis[s]*di;
    float2 rv = bf2f2(((const u32*)(xw + (size_t)s*128))[t]);
    ax += w*rv.x; ay += w*rv.y;
  }
  for (; e + 4 <= hi; e += 4){
    ushort4 c4 = *(const ushort4*)(col + e);
    int s0 = c4.x, s1 = c4.y, s2 = c4.z, s3 = c4.w;
    float wA = dis[s0]*di, wB = dis[s1]*di, wC = dis[s2]*di, wD = dis[s3]*di;
    float2 r0 = bf2f2(((const u32*)(xw + (size_t)s0*128))[t]);
    float2 r1 = bf2f2(((const u32*)(xw + (size_t)s1*128))[t]);
    float2 r2 = bf2f2(((const u32*)(xw + (size_t)s2*128))[t]);
    float2 r3 = bf2f2(((const u32*)(xw + (size_t)s3*128))[t]);
    ax += wA*r0.x; ay += wA*r0.y;
    ax += wB*r1.x; ay += wB*r1.y;
    ax += wC*r2.x; ay += wC*r2.y;
    ax += wD*r3.x; ay += wD*r3.y;
  }
  for (; e < hi; ++e){
    int s = col[e];
    float w = dis[s]*di;
    float2 rv = bf2f2(((const u32*)(xw + (size_t)s*128))[t]);
    ax += w*rv.x; ay += w*rv.y;
  }
  ((u32*)(out + (size_t)i*128))[t] = pack_bf2(ax, ay);
}

// ---------------- BatchNorm (GCN1 path: vectorized partials, feature-major) -----
__global__ void k_bn_part(const u16* x, int stride, int W, float* part){
  __shared__ float shs[8][132];
  __shared__ float shq[8][132];
  int t = threadIdx.x;
  int ft = t & 31, rl = t >> 5;
  int f0 = ft*4;
  int fbase = blockIdx.x*128;
  int p = blockIdx.y;
  float s0=0.f,s1=0.f,s2=0.f,s3=0.f, q0=0.f,q1=0.f,q2=0.f,q3=0.f;
  for (int r = p + PBN*rl; r < NN; r += PBN*8){
    ushort4 u = *(const ushort4*)(x + (size_t)r*stride + fbase + f0);
    float v0 = bf2f(u.x), v1 = bf2f(u.y), v2 = bf2f(u.z), v3 = bf2f(u.w);
    s0 += v0; s1 += v1; s2 += v2; s3 += v3;
    q0 += v0*v0; q1 += v1*v1; q2 += v2*v2; q3 += v3*v3;
  }
  shs[rl][f0] = s0; shs[rl][f0+1] = s1; shs[rl][f0+2] = s2; shs[rl][f0+3] = s3;
  shq[rl][f0] = q0; shq[rl][f0+1] = q1; shq[rl][f0+2] = q2; shq[rl][f0+3] = q3;
  __syncthreads();
  if (t < 128){
    float s = 0.f, q = 0.f;
    #pragma unroll
    for (int r = 0; r < 8; ++r){ s += shs[r][t]; q += shq[r][t]; }
    size_t fb = (size_t)(fbase + t)*2*PBN;
    part[fb + p] = s;
    part[fb + PBN + p] = q;
  }
}
__global__ void k_bn_fin(const float* part, const float* g, const float* be,
                         float* ss, int W, float invn){
  __shared__ float rs[256], rq[256];
  int f = blockIdx.x, t = threadIdx.x;
  size_t fb = (size_t)f*2*PBN;
  rs[t] = part[fb + t];
  rq[t] = part[fb + PBN + t];
  __syncthreads();
  for (int st = 128; st; st >>= 1){
    if (t < st){ rs[t] += rs[t+st]; rq[t] += rq[t+st]; }
    __syncthreads();
  }
  if (t == 0){
    float mean = rs[0]*invn;
    float var  = rq[0]*invn - mean*mean;
    float sc = g[f]*rsqrtf(var + EPSV);
    ss[f] = sc;
    ss[W+f] = be[f] - mean*sc;
  }
}
// finisher for mm-fused partials (NB slots, feature-major)
__global__ void k_bn_finB(const float* part, int NB, const float* g, const float* be,
                          float* ss, int W, float invn){
  __shared__ float rs[256], rq[256];
  int f = blockIdx.x, t = threadIdx.x;
  size_t fb = (size_t)f*2*NB;
  float s = 0.f, q = 0.f;
  for (int b = t; b < NB; b += 256){ s += part[fb + b]; q += part[fb + NB + b]; }
  rs[t] = s; rq[t] = q;
  __syncthreads();
  for (int st = 128; st; st >>= 1){
    if (t < st){ rs[t] += rs[t+st]; rq[t] += rq[t+st]; }
    __syncthreads();
  }
  if (t == 0){
    float mean = rs[0]*invn;
    float var  = rq[0]*invn - mean*mean;
    float sc = g[f]*rsqrtf(var + EPSV);
    ss[f] = sc;
    ss[W+f] = be[f] - mean*sc;
  }
}
template<bool RES>
__global__ void k_bn_apply(const u32* x, const float* ss, const u32* res, u32* out){
  const int n = NN*64;
  for (int idx = blockIdx.x*256 + threadIdx.x; idx < n; idx += gridDim.x*256){
    int f2 = (idx & 63)*2;
    float2 v = bf2f2(x[idx]);
    v.x = gelu_f(v.x*ss[f2]   + ss[128+f2]);
    v.y = gelu_f(v.y*ss[f2+1] + ss[128+f2+1]);
    if (RES){ float2 r = bf2f2(res[idx]); v.x += r.x; v.y += r.y; }
    out[idx] = pack_bf2(v.x, v.y);
  }
}

// ---------------- GAT ----------------
__global__ void k_wv(const float* w_gat, const float* att_s, const float* att_d,
                     float* wvs, float* wvd){
  int h = blockIdx.x, c = threadIdx.x;   // 5 blocks x 128
  float ss = 0.f, sd = 0.f;
  const float* wr = w_gat + (size_t)c*640 + h*128;
  const float* as = att_s + h*128;
  const float* ad = att_d + h*128;
  for (int k = 0; k < 128; ++k){
    float wv = wr[k];
    ss += wv*as[k]; sd += wv*ad[k];
  }
  wvs[h*128+c] = ss; wvd[h*128+c] = sd;
}

// per-node scores; stride-8 output so per-edge loads are one aligned float4+float
__global__ void k_score10(const u16* h2, const float* wvs, const float* wvd,
                          float* asrc8, float* adst8){
  int i = blockIdx.x, t = threadIdx.x;   // 64
  float2 v = bf2f2(((const u32*)(h2 + (size_t)i*128))[t]);
  int f2 = 2*t;
  #pragma unroll
  for (int h = 0; h < 5; ++h){
    float vs = v.x*wvs[h*128+f2] + v.y*wvs[h*128+f2+1];
    float vd = v.x*wvd[h*128+f2] + v.y*wvd[h*128+f2+1];
    #pragma unroll
    for (int d = 32; d; d >>= 1){ vs += __shfl_xor(vs, d); vd += __shfl_xor(vd, d); }
    if (t == 0){ asrc8[i*8+h] = vs; adst8[i*8+h] = vd; }
  }
}

// fused softmax + gather, ONE edge pass, chunked.
// Phase 1: lane t computes the 5 alphas for edge base+t ONCE, packs
//          {a0..a3, a4, colbits} into one 32B LDS line, owner-lane dn.
// Phase 2: 2-way unrolled; per edge: 1 float4 + 1 float2 LDS read (broadcast),
//          1 global row load, 10 FMA.
__global__ void k_gat_fused(const u16* h2, const int* off, const u16* col,
                            const float* asrc8, const float* adst8,
                            u16* agg5){
  __shared__ float sal[64][8];   // 32B line per edge: a0..a3, a4, colbits, pad
  int i = blockIdx.x, t = threadIdx.x;   // 64
  float2 svv = bf2f2(((const u32*)(h2 + (size_t)i*128))[t]);
  float ad[5], dn[5], ax[5], ay[5];
  float esf[5];
  #pragma unroll
  for (int h = 0; h < 5; ++h){
    ad[h] = adst8[i*8+h];
    float v = asrc8[i*8+h] + ad[h];
    v = (v > 0.f) ? v : 0.2f*v;
    esf[h] = expf(v);                  // self-loop numerator (all lanes identical)
    dn[h] = 0.f;
    ax[h] = esf[h]*svv.x; ay[h] = esf[h]*svv.y;
  }
  int lo = off[i], hi = off[i+1];
  for (int base = lo; base < hi; base += 64){
    int n = min(64, hi - base);
    if (t < n){
      u32 s = col[base + t];
      float4 a03 = *(const float4*)(asrc8 + (size_t)s*8);
      float  a4  = asrc8[(size_t)s*8 + 4];
      float sa[5] = {a03.x, a03.y, a03.z, a03.w, a4};
      float ex[5];
      #pragma unroll
      for (int h = 0; h < 5; ++h){
        float v = sa[h] + ad[h];
        v = (v > 0.f) ? v : 0.2f*v;
        ex[h] = expf(v);
        dn[h] += ex[h];                // owner-lane dn contribution
      }
      float4 w0 = {ex[0], ex[1], ex[2], ex[3]};
      *(float4*)&sal[t][0] = w0;
      sal[t][4] = ex[4];
      sal[t][5] = __uint_as_float(s);
    }
    __syncthreads();
    int j = 0;
    for (; j + 2 <= n; j += 2){
      float4 p0 = *(const float4*)&sal[j][0];
      float2 q0 = *(const float2*)&sal[j][4];
      float4 p1 = *(const float4*)&sal[j+1][0];
      float2 q1 = *(const float2*)&sal[j+1][4];
      u32 s0 = __float_as_uint(q0.y), s1 = __float_as_uint(q1.y);
      float2 r0 = bf2f2(((const u32*)(h2 + (size_t)s0*128))[t]);
      float2 r1 = bf2f2(((const u32*)(h2 + (size_t)s1*128))[t]);
      ax[0] += p0.x*r0.x + p1.x*r1.x; ay[0] += p0.x*r0.y + p1.x*r1.y;
      ax[1] += p0.y*r0.x + p1.y*r1.x; ay[1] += p0.y*r0.y + p1.y*r1.y;
      ax[2] += p0.z*r0.x + p1.z*r1.x; ay[2] += p0.z*r0.y + p1.z*r1.y;
      ax[3] += p0.w*r0.x + p1.w*r1.x; ay[3] += p0.w*r0.y + p1.w*r1.y;
      ax[4] += q0.x*r0.x + q1.x*r1.x; ay[4] += q0.x*r0.y + q1.x*r1.y;
    }
    if (j < n){
      float4 p0 = *(const float4*)&sal[j][0];
      float2 q0 = *(const float2*)&sal[j][4];
      u32 s0 = __float_as_uint(q0.y);
      float2 r0 = bf2f2(((const u32*)(h2 + (size_t)s0*128))[t]);
      ax[0] += p0.x*r0.x; ay[0] += p0.x*r0.y;
      ax[1] += p0.y*r0.x; ay[1] += p0.y*r0.y;
      ax[2] += p0.z*r0.x; ay[2] += p0.z*r0.y;
      ax[3] += p0.w*r0.x; ay[3] += p0.w*r0.y;
      ax[4] += q0.x*r0.x; ay[4] += q0.x*r0.y;
    }
    __syncthreads();
  }
  #pragma unroll
  for (int h = 0; h < 5; ++h){
    #pragma unroll
    for (int d = 32; d; d >>= 1) dn[h] += __shfl_xor(dn[h], d);
    float iv = 1.f/fmaxf(dn[h] + esf[h], 1e-16f);
    ((u32*)(agg5 + (size_t)i*640 + h*128))[t] = pack_bf2(ax[h]*iv, ay[h]*iv);
  }
}

// ---------------- fused graph-LN stats + mean pool (single pass over A512) -------
__global__ void k_gstart(const int* batch, int* gs){
  int g = threadIdx.x;
  if (g > NG) return;
  int lo = 0, hi = NN;
  while (lo < hi){ int mid = (lo+hi) >> 1; if (batch[mid] < g) lo = mid+1; else hi = mid; }
  gs[g] = lo;
}
// grid (NG, SPL) x 512 threads: 128 f-threads (ushort4) x 4 row lanes
__global__ void k_poolstat(const u16* a512, const float* ss, const int* gs,
                           float* poolpart, float* sqpart){
  __shared__ float4 red4[512];
  __shared__ float redq[512];
  int g = blockIdx.x, sp = blockIdx.y, t = threadIdx.x;
  int ft = t & 127, rl = t >> 7;
  int f0 = ft*4;
  int lo = gs[g], hi = gs[g+1];
  float sc0 = ss[f0],     sc1 = ss[f0+1],     sc2 = ss[f0+2],     sc3 = ss[f0+3];
  float sh0 = ss[512+f0], sh1 = ss[512+f0+1], sh2 = ss[512+f0+2], sh3 = ss[512+f0+3];
  float4 s4 = {0.f,0.f,0.f,0.f};
  float q = 0.f;
  for (int r = lo + sp*4 + rl; r < hi; r += SPL*4){
    ushort4 u = *(const ushort4*)(a512 + (size_t)r*512 + f0);
    float v0 = gelu_f(bf2f(u.x)*sc0 + sh0);
    float v1 = gelu_f(bf2f(u.y)*sc1 + sh1);
    float v2 = gelu_f(bf2f(u.z)*sc2 + sh2);
    float v3 = gelu_f(bf2f(u.w)*sc3 + sh3);
    s4.x += v0; s4.y += v1; s4.z += v2; s4.w += v3;
    q += v0*v0 + v1*v1 + v2*v2 + v3*v3;
  }
  red4[t] = s4; redq[t] = q;
  __syncthreads();
  for (int st = 256; st; st >>= 1){
    if (t < st) redq[t] += redq[t+st];
    __syncthreads();
  }
  if (t == 0) sqpart[g*SPL + sp] = redq[0];
  if (rl == 0){
    float4 a = red4[t], b = red4[t+128], c = red4[t+256], d = red4[t+384];
    float4 o;
    o.x = a.x+b.x+c.x+d.x; o.y = a.y+b.y+c.y+d.y;
    o.z = a.z+b.z+c.z+d.z; o.w = a.w+b.w+c.w+d.w;
    ((float4*)poolpart)[((size_t)(g*SPL + sp))*128 + ft] = o;
  }
}
// stage A: PRB blocks x 256 threads, deterministic block partials
__global__ void k_poolredA(const float* poolpart, const float* sqpart,
                           float* ppred, float* sqred){
  __shared__ float rs_[256], rq_[256];
  int b = blockIdx.x, t = threadIdx.x;
  float s = 0.f, q = 0.f;
  const int tot = NG*SPL*512;
  for (int i = b*256 + t; i < tot; i += PRB*256) s += poolpart[i];
  for (int i = b*256 + t; i < NG*SPL; i += PRB*256) q += sqpart[i];
  rs_[t] = s; rq_[t] = q;
  __syncthreads();
  for (int st = 128; st; st >>= 1){
    if (t < st){ rs_[t] += rs_[t+st]; rq_[t] += rq_[t+st]; }
    __syncthreads();
  }
  if (t == 0){ ppred[b] = rs_[0]; sqred[b] = rq_[0]; }
}
__global__ void k_poolredB(const float* ppred, const float* sqred, float* scal){
  __shared__ float rs_[128], rq_[128];
  int t = threadIdx.x;   // 128 = PRB
  rs_[t] = ppred[t]; rq_[t] = sqred[t];
  __syncthreads();
  for (int st = 64; st; st >>= 1){
    if (t < st){ rs_[t] += rs_[t+st]; rq_[t] += rq_[t+st]; }
    __syncthreads();
  }
  if (t == 0){
    float invn = 1.f/((float)NN*512.f);
    float mu  = rs_[0]*invn;
    float var = rq_[0]*invn - mu*mu;
    scal[2] = mu;
    scal[3] = rsqrtf(var + EPSV);
  }
}
__global__ void k_poolapply(const float* poolpart, const int* gs, const float* scal,
                            const float* gam, const float* bet, float* pooled){
  int g = blockIdx.x, f = threadIdx.x;   // 512
  float s = 0.f;
  #pragma unroll
  for (int sp = 0; sp < SPL; ++sp)
    s += poolpart[((size_t)(g*SPL + sp))*512 + f];
  float cnt = (float)max(gs[g+1] - gs[g], 1);
  pooled[g*512 + f] = (s/cnt - scal[2])*scal[3]*gam[f] + bet[f];
}

// ---------------- projection head + classifier (fp32, tiny) ----------------
__global__ void k_head_mm1(const float* pooled, const float* w, const float* b, float* q){
  int g = blockIdx.x, j = threadIdx.x;   // 128
  float s = b[j];
  const float* pr = pooled + g*512;
  for (int k = 0; k < 512; ++k) s += pr[k]*w[k*128+j];
  q[g*128+j] = s;
}
__global__ void k_head_bn(const float* qin, const float* g_, const float* be_, float* qout){
  int f = threadIdx.x;   // 128, single block
  float s = 0.f, sq = 0.f;
  for (int r = 0; r < NG; ++r){ float v = qin[r*128+f]; s += v; sq += v*v; }
  float mu = s*(1.f/NG), var = sq*(1.f/NG) - mu*mu;
  float sc = g_[f]*rsqrtf(var + EPSV);
  float sh = be_[f] - mu*sc;
  for (int r = 0; r < NG; ++r) qout[r*128+f] = gelu_f(qin[r*128+f]*sc + sh);
}
// head2 (mm + res + LN + L2-normalize) fused with classifier (log-softmax)
__global__ void k_head2c(const float* q2, const float* w, const float* b,
                         const float* gam, const float* bet,
                         const float* wc, const float* bc, float* out){
  int g = blockIdx.x, j = threadIdx.x;   // 128
  __shared__ float row[128], red[128], shv[3];
  row[j] = q2[g*128+j];
  __syncthreads();
  float s = b[j] + row[j];
  for (int k = 0; k < 128; ++k) s += row[k]*w[k*128+j];
  red[j] = s; __syncthreads();
  for (int st = 64; st; st >>= 1){ if (j < st) red[j] += red[j+st]; __syncthreads(); }
  if (j == 0) shv[0] = red[0]*(1.f/128.f);
  __syncthreads();
  float d = s - shv[0];
  red[j] = d*d; __syncthreads();
  for (int st = 64; st; st >>= 1){ if (j < st) red[j] += red[j+st]; __syncthreads(); }
  if (j == 0) shv[1] = rsqrtf(red[0]*(1.f/128.f) + EPSV);
  __syncthreads();
  float v = d*shv[1]*gam[j] + bet[j];
  red[j] = v*v; __syncthreads();
  for (int st = 64; st; st >>= 1){ if (j < st) red[j] += red[j+st]; __syncthreads(); }
  if (j == 0) shv[2] = 1.f/fmaxf(sqrtf(red[0]), 1e-12f);
  __syncthreads();
  float o = v*shv[2];
  out[g*128+j] = o;
  __syncthreads();
  row[j] = o;        // x1 row for classifier
  __syncthreads();
  float cs = -1e30f;
  if (j < NC){
    cs = bc[j];
    for (int k = 0; k < 128; ++k) cs += row[k]*wc[k*NC+j];
  }
  red[j] = cs; __syncthreads();
  for (int st = 64; st; st >>= 1){ if (j < st) red[j] = fmaxf(red[j], red[j+st]); __syncthreads(); }
  if (j == 0) shv[0] = red[0];
  __syncthreads();
  float e = (j < NC) ? expf(cs - shv[0]) : 0.f;
  red[j] = e; __syncthreads();
  for (int st = 64; st; st >>= 1){ if (j < st) red[j] += red[j+st]; __syncthreads(); }
  if (j == 0) shv[1] = logf(red[0]);
  __syncthreads();
  if (j < NC) out[NG*128 + g*NC+j] = cs - shv[0] - shv[1];
}

extern "C" void kernel_launch(void* const* d_in, const int* in_sizes, int n_in,
                              void* d_out, int out_size, void* d_ws, size_t ws_size,
                              hipStream_t stream){
  const float* x      = (const float*)d_in[0];
  const int*   ei     = (const int*)d_in[1];
  const int*   batch  = (const int*)d_in[2];
  const float* w_in   = (const float*)d_in[3];
  const float* b_in   = (const float*)d_in[4];
  const float* g_in   = (const float*)d_in[5];
  const float* be_in  = (const float*)d_in[6];
  const float* w_h    = (const float*)d_in[7];
  const float* b_h    = (const float*)d_in[8];
  const float* g_h    = (const float*)d_in[9];
  const float* be_h   = (const float*)d_in[10];
  const float* w_gat  = (const float*)d_in[11];
  const float* att_s  = (const float*)d_in[12];
  const float* att_d  = (const float*)d_in[13];
  const float* b_gat  = (const float*)d_in[14];
  const float* w_out  = (const float*)d_in[15];
  const float* b_out  = (const float*)d_in[16];
  const float* g_out  = (const float*)d_in[17];
  const float* be_out = (const float*)d_in[18];
  const float* g_ln   = (const float*)d_in[19];
  const float* be_ln  = (const float*)d_in[20];
  const float* w_p1   = (const float*)d_in[21];
  const float* b_p1   = (const float*)d_in[22];
  const float* g_pbn  = (const float*)d_in[23];
  const float* be_pbn = (const float*)d_in[24];
  const float* w_p2   = (const float*)d_in[25];
  const float* b_p2   = (const float*)d_in[26];
  const float* g_pln  = (const float*)d_in[27];
  const float* be_pln = (const float*)d_in[28];
  const float* w_c    = (const float*)d_in[29];
  const float* b_c    = (const float*)d_in[30];
  float* out = (float*)d_out;

  char* ws = (char*)d_ws;
  size_t o = 0;
  auto carve = [&](size_t bytes) -> char* {
    char* p = ws + o;
    o += (bytes + 255) & ~(size_t)255;
    return p;
  };
  int*   deg    = (int*)  carve((size_t)NN*4);
  int*   off    = (int*)  carve((size_t)(NN+1)*4);
  int*   cur    = (int*)  carve((size_t)NN*4);
  u16*   col    = (u16*)  carve((size_t)NE*2);       // 1.6 MB (u16 node ids)
  float* dis    = (float*)carve((size_t)NN*4);
  int*   bsum   = (int*)  carve((size_t)SCB*4);
  int*   boff   = (int*)  carve((size_t)(SCB+1)*4);
  float* aggx3  = (float*)carve((size_t)NN*3*4);
  u16*   F0     = (u16*)  carve((size_t)NN*128*2);   // 12.8 MB
  u16*   F1     = (u16*)  carve((size_t)NN*128*2);
  u16*   F2     = (u16*)  carve((size_t)NN*128*2);
  u16*   AGG5   = (u16*)  carve((size_t)NN*640*2);   // 64 MB; later aliased as A512
  float* asrc8  = (float*)carve((size_t)NN*8*4);     // 1.6 MB stride-8
  float* adst8  = (float*)carve((size_t)NN*8*4);
  float* wvs    = (float*)carve(640*4);
  float* wvd    = (float*)carve(640*4);
  u16*   BfH    = (u16*)  carve((size_t)128*128*2);
  u16*   BfG    = (u16*)  carve((size_t)640*128*2);
  u16*   BfO    = (u16*)  carve((size_t)128*512*2);
  float* part   = (float*)carve((size_t)512*2*MMB*4);   // 3.2 MB (feature-major, max slots)
  float* poolpart = (float*)carve((size_t)NG*SPL*512*4); // 1 MB
  float* sqpart = (float*)carve((size_t)NG*SPL*4);
  float* ppred  = (float*)carve((size_t)PRB*4);
  float* sqred  = (float*)carve((size_t)PRB*4);
  float* ssbuf  = (float*)carve(1024*4);
  float* scal   = (float*)carve(64);
  int*   gst    = (int*)  carve(65*4);
  float* pooled = (float*)carve((size_t)NG*512*4);
  float* q      = (float*)carve((size_t)NG*128*4);
  float* q2     = (float*)carve((size_t)NG*128*4);
  if (o > ws_size) return;   // ~119 MB total

  u16* A512 = AGG5;        // [NN,512] bf16 reuses AGG5 (dead by then)

  // ---- CSR build ----
  k_deg_init<<<196,256,0,stream>>>(deg);
  k_deg_hist<<<3125,256,0,stream>>>(ei, deg);
  k_scanA<<<SCB,256,0,stream>>>(deg, bsum, dis);
  k_scanB<<<1,256,0,stream>>>(bsum, boff);
  k_scanC<<<SCB,256,0,stream>>>(deg, boff, off, cur);
  k_scatter<<<3125,256,0,stream>>>(ei, cur, col);

  // ---- weight fragment pre-conversion (tiny, one-time) ----
  k_prepB<<<64,256,0,stream>>>(w_h, 128, 128, 1, BfH);
  k_prepBG<<<320,256,0,stream>>>(w_gat, BfG);
  k_prepB<<<256,256,0,stream>>>(w_out, 512, 128, 4, BfO);

  // ---- GCN1: agg in 3-dim, mm 3->128, BN, gelu ----
  k_agg3<<<196,256,0,stream>>>(x, off, col, dis, aggx3);
  k_mm_in<<<(NN*64+255)/256,256,0,stream>>>(aggx3, w_in, b_in, (u32*)F0);   // pre1=F0
  k_bn_part<<<dim3(1,PBN),256,0,stream>>>(F0, 128, 128, part);
  k_bn_fin<<<128,256,0,stream>>>(part, g_in, be_in, ssbuf, 128, 1.f/NN);
  k_bn_apply<false><<<2048,256,0,stream>>>((u32*)F0, ssbuf, nullptr, (u32*)F1); // h1=F1

  // ---- GCN2: agg(h1), mm 128->128 +b (fused BN stats), BN, gelu, +res ----
  k_gcn_agg64<<<NN,64,0,stream>>>(F1, off, col, dis, F0);                   // aggH1=F0
  k_mm_mfma<<<dim3(MMB,1),256,0,stream>>>(F0, 128, NN, 128, BfH, F2, 128, b_h, part); // pre2=F2
  k_bn_finB<<<128,256,0,stream>>>(part, MMB, g_h, be_h, ssbuf, 128, 1.f/NN);
  k_bn_apply<true><<<2048,256,0,stream>>>((u32*)F2, ssbuf, (u32*)F1, (u32*)F0);  // h2=F0

  // ---- GAT: scores from h2, ONE fused softmax+gather edge pass, mm K=640 ----
  k_wv<<<5,128,0,stream>>>(w_gat, att_s, att_d, wvs, wvd);
  k_score10<<<NN,64,0,stream>>>(F0, wvs, wvd, asrc8, adst8);
  k_gat_fused<<<NN,64,0,stream>>>(F0, off, col, asrc8, adst8, AGG5);
  k_mm_mfma<<<dim3(MMB,1),256,0,stream>>>(AGG5, 640, NN, 640, BfG, F1, 128, b_gat, nullptr); // h3=F1

  // ---- GCN3: agg(h3), mm 128->512 +b (fused BN stats, 4 col chunks) ----
  k_gcn_agg64<<<NN,64,0,stream>>>(F1, off, col, dis, F2);                   // aggH3=F2
  k_mm_mfma<<<dim3(MMB,4),256,0,stream>>>(F2, 128, NN, 128, BfO, A512, 512, b_out, part); // pre4=A512
  k_bn_finB<<<512,256,0,stream>>>(part, MMB, g_out, be_out, ssbuf, 512, 1.f/NN);

  // ---- fused graph-LN stats + mean pool (single pass; h4 never materialized) ----
  k_gstart<<<1,128,0,stream>>>(batch, gst);
  k_poolstat<<<dim3(NG,SPL),512,0,stream>>>(A512, ssbuf, gst, poolpart, sqpart);
  k_poolredA<<<PRB,256,0,stream>>>(poolpart, sqpart, ppred, sqred);
  k_poolredB<<<1,128,0,stream>>>(ppred, sqred, scal);
  k_poolapply<<<NG,512,0,stream>>>(poolpart, gst, scal, g_ln, be_ln, pooled);

  // ---- projection head + classifier ----
  k_head_mm1<<<NG,128,0,stream>>>(pooled, w_p1, b_p1, q);
  k_head_bn<<<1,128,0,stream>>>(q, g_pbn, be_pbn, q2);
  k_head2c<<<NG,128,0,stream>>>(q2, w_p2, b_p2, g_pln, be_pln, w_c, b_c, out);
}